// Round 2
// baseline (401.829 us; speedup 1.0000x reference)
//
#include <hip/hip_runtime.h>
#include <hip/hip_cooperative_groups.h>
#include <cstddef>
#include <cstdint>

namespace cg = cooperative_groups;

// MambaDoc — round 15: fuse chunkstate+statecombine+ssd into ONE cooperative
// kernel per layer (2 grid syncs). Block (c,h,b) identical across the three
// old kernels, so convs run ONCE (XT/Btok/Ctok/BTw persist in LDS across the
// grid syncs), ssd's zx16 X/B/C re-read (~25 MB/layer) is deleted, and Hin is
// consumed directly from global (raw LDS buffer freed -> everything fits in
// 137 KB). Launches 11 -> 7. gemm_rms0 / gemm_inproj / gemm_outrms unchanged.

#define LSEQ 4096

typedef unsigned short u16;
typedef _Float16 f16x8 __attribute__((ext_vector_type(8)));
typedef float f32x4 __attribute__((ext_vector_type(4)));

__device__ __forceinline__ u16 f2h(float x) {
    return __builtin_bit_cast(u16, (_Float16)x);
}
__device__ __forceinline__ float h2f(u16 u) {
    return (float)__builtin_bit_cast(_Float16, u);
}
__device__ __forceinline__ float silu_f(float x) { return x / (1.f + __expf(-x)); }

__device__ __forceinline__ void async_lds16(const void* g, void* l) {
    __builtin_amdgcn_global_load_lds(
        (const __attribute__((address_space(1))) unsigned int*)g,
        (__attribute__((address_space(3))) unsigned int*)l, 16, 0, 0);
}

__device__ __forceinline__ uint4 cvt8(const float* __restrict__ src) {
    float4 a = *(const float4*)src;
    float4 b = *(const float4*)(src + 4);
    union { u16 u[8]; uint4 q; } pk;
    pk.u[0] = f2h(a.x); pk.u[1] = f2h(a.y); pk.u[2] = f2h(a.z); pk.u[3] = f2h(a.w);
    pk.u[4] = f2h(b.x); pk.u[5] = f2h(b.y); pk.u[6] = f2h(b.z); pk.u[7] = f2h(b.w);
    return pk.q;
}

__device__ __forceinline__ uint4 cvt8g(const float* __restrict__ src,
                                       const float* __restrict__ gw) {
    float4 a = *(const float4*)src;
    float4 b = *(const float4*)(src + 4);
    float4 ga = *(const float4*)gw;
    float4 gb = *(const float4*)(gw + 4);
    union { u16 u[8]; uint4 q; } pk;
    pk.u[0] = f2h(a.x * ga.x); pk.u[1] = f2h(a.y * ga.y);
    pk.u[2] = f2h(a.z * ga.z); pk.u[3] = f2h(a.w * ga.w);
    pk.u[4] = f2h(b.x * gb.x); pk.u[5] = f2h(b.y * gb.y);
    pk.u[6] = f2h(b.z * gb.z); pk.u[7] = f2h(b.w * gb.w);
    return pk.q;
}

// ---------------------------------------------------------------------------
// Initial projection + fused RMSNorm. BM=64, grid (1,256). (unchanged)
// ---------------------------------------------------------------------------
__global__ __launch_bounds__(256) void gemm_rms0_kernel(
    const float* __restrict__ xf, const float* __restrict__ wf,
    const float* __restrict__ bias, const float* __restrict__ rmsw,
    u16* __restrict__ xp16, u16* __restrict__ hbuf16, u16* __restrict__ hn16)
{
    __shared__ u16 sA[64 * 64];
    __shared__ u16 sW[128 * 64];
    __shared__ float red[64][33];
    __shared__ float srstd[64];
    const int m0 = blockIdx.y * 64;
    const int tid = threadIdx.x, wid = tid >> 6, lane = tid & 63;
    const int wm = (wid >> 1) * 32, wn = (wid & 1) * 64;
    const int quad = lane >> 4, cl = lane & 15;
    #pragma unroll
    for (int i = 0; i < 2; i++) {
        int ck = i * 256 + tid;
        int r = ck >> 3, cc = ck & 7;
        int csw = (cc ^ (r & 7)) << 3;
        *(uint4*)&sA[ck * 8] = cvt8(xf + (size_t)(m0 + r) * 64 + csw);
    }
    #pragma unroll
    for (int i = 0; i < 4; i++) {
        int ck = i * 256 + tid;
        int r = ck >> 3, cc = ck & 7;
        int csw = (cc ^ (r & 7)) << 3;
        *(uint4*)&sW[ck * 8] = cvt8(wf + (size_t)r * 64 + csw);
    }
    __syncthreads();
    f32x4 acc[2][4];
    #pragma unroll
    for (int i = 0; i < 2; i++)
        #pragma unroll
        for (int j = 0; j < 4; j++) acc[i][j] = f32x4{0.f, 0.f, 0.f, 0.f};
    #pragma unroll
    for (int ks = 0; ks < 2; ks++) {
        f16x8 af[2], wv[4];
        int kc = ks * 4 + quad;
        #pragma unroll
        for (int i = 0; i < 2; i++) {
            int r = wm + i * 16 + cl;
            af[i] = *(const f16x8*)&sA[r * 64 + ((kc ^ (r & 7)) << 3)];
        }
        #pragma unroll
        for (int j = 0; j < 4; j++) {
            int r = wn + j * 16 + cl;
            wv[j] = *(const f16x8*)&sW[r * 64 + ((kc ^ (r & 7)) << 3)];
        }
        #pragma unroll
        for (int i = 0; i < 2; i++)
            #pragma unroll
            for (int j = 0; j < 4; j++)
                acc[i][j] = __builtin_amdgcn_mfma_f32_16x16x32_f16(
                    af[i], wv[j], acc[i][j], 0, 0, 0);
    }
    const int slot = (wid & 1) * 16 + cl;
    #pragma unroll
    for (int i = 0; i < 2; i++)
        #pragma unroll
        for (int r = 0; r < 4; r++) {
            int t = wm + i * 16 + quad * 4 + r;
            float ssp = 0.f;
            #pragma unroll
            for (int j = 0; j < 4; j++) {
                int n = wn + j * 16 + cl;
                float v = acc[i][j][r] + bias[n];
                acc[i][j][r] = v;
                ssp += v * v;
            }
            red[t][slot] = ssp;
        }
    __syncthreads();
    if (tid < 64) {
        float s = 0.f;
        #pragma unroll
        for (int sl = 0; sl < 32; sl++) s += red[tid][sl];
        srstd[tid] = rsqrtf(s * (1.f / 128.f) + 1e-5f);
    }
    __syncthreads();
    #pragma unroll
    for (int i = 0; i < 2; i++)
        #pragma unroll
        for (int r = 0; r < 4; r++) {
            int t = wm + i * 16 + quad * 4 + r;
            size_t ob = (size_t)(m0 + t) * 128;
            float rstd = srstd[t];
            #pragma unroll
            for (int j = 0; j < 4; j++) {
                int n = wn + j * 16 + cl;
                float v = acc[i][j][r];
                u16 vh = f2h(v);
                xp16[ob + n] = vh;
                hbuf16[ob + n] = vh;
                hn16[ob + n] = f2h(v * rstd * rmsw[n]);
            }
        }
}

// ---------------------------------------------------------------------------
// in_proj GEMM fp16 (K=128). Grid (7, 128). (unchanged)
// ---------------------------------------------------------------------------
__global__ __launch_bounds__(256) void gemm_inproj_kernel(
    const u16* __restrict__ A, const float* __restrict__ Wf,
    u16* __restrict__ zx16, float* __restrict__ dtb, float* __restrict__ Sb,
    const float* __restrict__ dt_bias, const float* __restrict__ A_log)
{
    __shared__ u16 sA[128 * 64];
    __shared__ u16 sW[128 * 64];
    __shared__ float sdt[2][128];
    const int K = 128, N = 770;
    const int n0 = blockIdx.x * 128, m0 = blockIdx.y * 128;
    const int tid = threadIdx.x, wid = tid >> 6, lane = tid & 63;
    const int wm = (wid >> 1) * 64, wn = (wid & 1) * 64;
    const int quad = lane >> 4, cl = lane & 15;
    f32x4 acc[4][4];
    #pragma unroll
    for (int i = 0; i < 4; i++)
        #pragma unroll
        for (int j = 0; j < 4; j++) acc[i][j] = f32x4{0.f, 0.f, 0.f, 0.f};

    for (int k0 = 0; k0 < K; k0 += 64) {
        #pragma unroll
        for (int i = 0; i < 4; i++) {
            int ck = i * 256 + tid;
            int r = ck >> 3, cc = ck & 7;
            int csw = (cc ^ (r & 7)) << 3;
            async_lds16(A + (size_t)(m0 + r) * K + k0 + csw,
                        (void*)(sA + (i * 256 + (tid & ~63)) * 8));
        }
        #pragma unroll
        for (int i = 0; i < 4; i++) {
            int ck = i * 256 + tid;
            int r = ck >> 3, cc = ck & 7;
            int csw = (cc ^ (r & 7)) << 3;
            int rr = n0 + r; if (rr >= N) rr = N - 1;
            *(uint4*)&sW[ck * 8] = cvt8(Wf + (size_t)rr * K + k0 + csw);
        }
        __syncthreads();
        #pragma unroll
        for (int ks = 0; ks < 2; ks++) {
            f16x8 af[4], wv[4];
            int kc = ks * 4 + quad;
            #pragma unroll
            for (int i = 0; i < 4; i++) {
                int r = wm + i * 16 + cl;
                af[i] = *(const f16x8*)&sA[r * 64 + ((kc ^ (r & 7)) << 3)];
            }
            #pragma unroll
            for (int j = 0; j < 4; j++) {
                int r = wn + j * 16 + cl;
                wv[j] = *(const f16x8*)&sW[r * 64 + ((kc ^ (r & 7)) << 3)];
            }
            #pragma unroll
            for (int i = 0; i < 4; i++)
                #pragma unroll
                for (int j = 0; j < 4; j++)
                    acc[i][j] = __builtin_amdgcn_mfma_f32_16x16x32_f16(
                        af[i], wv[j], acc[i][j], 0, 0, 0);
        }
        __syncthreads();
    }
    if (blockIdx.x < 6) {
        #pragma unroll
        for (int i = 0; i < 4; i++) {
            int m = m0 + wm + i * 16 + quad * 4;
            #pragma unroll
            for (int j = 0; j < 4; j++) {
                int n = n0 + wn + j * 16 + cl;
                #pragma unroll
                for (int r = 0; r < 4; r++)
                    zx16[(size_t)(m + r) * 768 + n] = f2h(acc[i][j][r]);
            }
        }
    } else {
        if ((wid & 1) == 0 && cl < 2) {
            #pragma unroll
            for (int i = 0; i < 4; i++)
                #pragma unroll
                for (int r = 0; r < 4; r++)
                    sdt[cl][wm + i * 16 + quad * 4 + r] = acc[i][0][r];
        }
        __syncthreads();
        const int hh = tid >> 7, t = tid & 127;
        float raw = sdt[hh][t] + dt_bias[hh];
        float dt = fmaxf(raw, 0.f) + log1pf(__expf(-fabsf(raw)));
        dtb[(size_t)(m0 + t) * 2 + hh] = dt;
        float ad = -__expf(A_log[hh]) * dt;
        __syncthreads();
        sdt[hh][t] = ad;
        __syncthreads();
        for (int off = 1; off < 128; off <<= 1) {
            float add = (t >= off) ? sdt[hh][t - off] : 0.f;
            __syncthreads();
            sdt[hh][t] += add;
            __syncthreads();
        }
        Sb[(size_t)(m0 + t) * 2 + hh] = sdt[hh][t];
    }
}

// ---------------------------------------------------------------------------
// Fused chunkstate + statecombine + SSD. Cooperative, grid (32,2,4), 512 thr,
// ~137 KB LDS, 1 block/CU, 256 blocks = 256 CUs.
//   Phase A: convs X/B/C once -> XT, Btok, Ctok, BTw(weighted); Hb = XT·BTw^T
//   grid.sync()
//   Phase B: inter-chunk scan Hb -> Hbf (tid<256, layout of old statecombine)
//   grid.sync()
//   Phase C: Y = Ctok·Hin^T (Hin straight from global) ; S = Ctok·Btok^T ;
//            G -> BTw (dead after phase A) ; Y += G·XT ; epilogue.
// ---------------------------------------------------------------------------
__global__ __launch_bounds__(512) void fused_mamba_kernel(
    const u16* __restrict__ zx16, const float* __restrict__ cw,
    const float* __restrict__ cb, const float* __restrict__ dtb,
    const float* __restrict__ Sb, u16* __restrict__ Hb,
    u16* __restrict__ Hbf, const float* __restrict__ Dp,
    u16* __restrict__ g16)
{
    __shared__ u16 XT[128 * 128];     // conv X, p-major (phases A, C3, epi)
    __shared__ u16 BTw[128 * 128];    // weighted B n-major (A); G (C2->C3)
    __shared__ u16 Btok[128 * 128];   // conv B token-major (C2)
    __shared__ u16 Ctok[128 * 128];   // conv C token-major (C1, C2)
    __shared__ float sS[128], sdt[128], ssw[128];
    __shared__ float scw[3][128][4];
    __shared__ float scb[3][128];
    __shared__ float sdec[32];
    const int c = blockIdx.x, h = blockIdx.y, b = blockIdx.z;
    const int tid = threadIdx.x, wid = tid >> 6, lane = tid & 63;
    const int quad = lane >> 4, cl = lane & 15;
    const int tok0 = b * LSEQ + c * 128;
    const size_t blk = ((size_t)((b * 2 + h) * 32 + c)) << 14;
    const int wm = (wid >> 1) * 32, wn = (wid & 1) * 64;

    // ---- tables
    for (int idx = tid; idx < 384; idx += 512) {
        int grp = idx >> 7, j = idx & 127;
        int ch = (grp == 0) ? (128 * h + j) : (grp == 1 ? 256 + j : 384 + j);
        float4 w4 = *(const float4*)&cw[ch * 4];
        scw[grp][j][0] = w4.x; scw[grp][j][1] = w4.y;
        scw[grp][j][2] = w4.z; scw[grp][j][3] = w4.w;
        scb[grp][j] = cb[ch];
    }
    if (tid < 128) {
        float Sv = Sb[(size_t)(tok0 + tid) * 2 + h];
        float dtv = dtb[(size_t)(tok0 + tid) * 2 + h];
        float Sl = Sb[(size_t)(tok0 + 127) * 2 + h];
        sS[tid] = Sv;
        sdt[tid] = dtv;
        ssw[tid] = __expf(Sl - Sv) * dtv;
    }
    // ---- register staging of all three conv inputs
    const int pg = tid >> 5, sb = tid & 31, s0 = sb * 4;
    const u16* gx = zx16 + 256 + 128 * h + pg * 8;
    const u16* gb = zx16 + 512 + pg * 8;
    const u16* gc = zx16 + 640 + pg * 8;
    uint4 vX[7], vB[7], vC[7];
    #pragma unroll
    for (int i = 0; i < 7; i++) {
        int q = s0 - 3 + i;
        bool zer = (c == 0) && (q < 0);
        int qq = zer ? 0 : q;
        size_t off = (size_t)(tok0 + qq) * 768;
        uint4 xv = *(const uint4*)(gx + off);
        uint4 bv = *(const uint4*)(gb + off);
        uint4 cv = *(const uint4*)(gc + off);
        vX[i] = zer ? make_uint4(0u, 0u, 0u, 0u) : xv;
        vB[i] = zer ? make_uint4(0u, 0u, 0u, 0u) : bv;
        vC[i] = zer ? make_uint4(0u, 0u, 0u, 0u) : cv;
    }
    __syncthreads();
    // ---- conv X -> XT (p-major)
    #pragma unroll
    for (int j = 0; j < 4; j++) {
        int s = s0 + j;
        f16x8 a0 = __builtin_bit_cast(f16x8, vX[j]);
        f16x8 a1 = __builtin_bit_cast(f16x8, vX[j + 1]);
        f16x8 a2 = __builtin_bit_cast(f16x8, vX[j + 2]);
        f16x8 a3 = __builtin_bit_cast(f16x8, vX[j + 3]);
        #pragma unroll
        for (int jj = 0; jj < 8; jj++) {
            int p = pg * 8 + jj;
            float o = scb[0][p] + (float)a0[jj] * scw[0][p][0]
                    + (float)a1[jj] * scw[0][p][1]
                    + (float)a2[jj] * scw[0][p][2]
                    + (float)a3[jj] * scw[0][p][3];
            XT[p * 128 + (((s >> 3) ^ (p & 15)) << 3) + (s & 7)] = f2h(silu_f(o));
        }
    }
    // ---- conv B -> Btok (token-major, unweighted) + BTw (n-major, *ssw[t])
    #pragma unroll
    for (int j = 0; j < 4; j++) {
        int t = s0 + j;
        float wsv = ssw[t];
        f16x8 a0 = __builtin_bit_cast(f16x8, vB[j]);
        f16x8 a1 = __builtin_bit_cast(f16x8, vB[j + 1]);
        f16x8 a2 = __builtin_bit_cast(f16x8, vB[j + 2]);
        f16x8 a3 = __builtin_bit_cast(f16x8, vB[j + 3]);
        union { u16 u[8]; uint4 q; } pk;
        #pragma unroll
        for (int jj = 0; jj < 8; jj++) {
            int n = pg * 8 + jj;
            float o = scb[1][n] + (float)a0[jj] * scw[1][n][0]
                    + (float)a1[jj] * scw[1][n][1]
                    + (float)a2[jj] * scw[1][n][2]
                    + (float)a3[jj] * scw[1][n][3];
            float so = silu_f(o);
            pk.u[jj] = f2h(so);
            BTw[n * 128 + (((t >> 3) ^ (n & 15)) << 3) + (t & 7)] = f2h(so * wsv);
        }
        *(uint4*)&Btok[t * 128 + ((pg ^ (t & 15)) << 3)] = pk.q;
    }
    // ---- conv C -> Ctok (token-major)
    #pragma unroll
    for (int j = 0; j < 4; j++) {
        int t = s0 + j;
        f16x8 a0 = __builtin_bit_cast(f16x8, vC[j]);
        f16x8 a1 = __builtin_bit_cast(f16x8, vC[j + 1]);
        f16x8 a2 = __builtin_bit_cast(f16x8, vC[j + 2]);
        f16x8 a3 = __builtin_bit_cast(f16x8, vC[j + 3]);
        union { u16 u[8]; uint4 q; } pk;
        #pragma unroll
        for (int jj = 0; jj < 8; jj++) {
            int n = pg * 8 + jj;
            float o = scb[2][n] + (float)a0[jj] * scw[2][n][0]
                    + (float)a1[jj] * scw[2][n][1]
                    + (float)a2[jj] * scw[2][n][2]
                    + (float)a3[jj] * scw[2][n][3];
            pk.u[jj] = f2h(silu_f(o));
        }
        *(uint4*)&Ctok[t * 128 + ((pg ^ (t & 15)) << 3)] = pk.q;
    }
    __syncthreads();
    // ---- phase A GEMM: Hb[p][n] = sum_s XT[p,s] * BTw[n,s]
    {
        f32x4 hacc[2][4];
        #pragma unroll
        for (int i = 0; i < 2; i++)
            #pragma unroll
            for (int j = 0; j < 4; j++) hacc[i][j] = f32x4{0.f, 0.f, 0.f, 0.f};
        #pragma unroll
        for (int ks = 0; ks < 4; ks++) {
            f16x8 xa[2], bb[4];
            int kc = ks * 4 + quad;
            #pragma unroll
            for (int i = 0; i < 2; i++) {
                int r = wm + i * 16 + cl;
                xa[i] = *(const f16x8*)&XT[r * 128 + ((kc ^ (r & 15)) << 3)];
            }
            #pragma unroll
            for (int j = 0; j < 4; j++) {
                int r = wn + j * 16 + cl;
                bb[j] = *(const f16x8*)&BTw[r * 128 + ((kc ^ (r & 15)) << 3)];
            }
            #pragma unroll
            for (int i = 0; i < 2; i++)
                #pragma unroll
                for (int j = 0; j < 4; j++)
                    hacc[i][j] = __builtin_amdgcn_mfma_f32_16x16x32_f16(
                        xa[i], bb[j], hacc[i][j], 0, 0, 0);
        }
        u16* out = Hb + blk;
        #pragma unroll
        for (int i = 0; i < 2; i++)
            #pragma unroll
            for (int j = 0; j < 4; j++)
                #pragma unroll
                for (int r = 0; r < 4; r++)
                    out[(size_t)(wm + i * 16 + quad * 4 + r) * 128
                        + wn + j * 16 + cl] = f2h(hacc[i][j][r]);
    }
    cg::this_grid().sync();
    // ---- phase B: inter-chunk combine (same layout as old statecombine)
    if (tid < 32)
        sdec[tid] = __expf(Sb[(size_t)(b * LSEQ + tid * 128 + 127) * 2 + h]);
    __syncthreads();
    if (tid < 256) {
        const int e2 = c * 256 + tid;
        const size_t base2 = ((size_t)((b * 2 + h) * 32)) << 13;
        const unsigned int* src = (const unsigned int*)Hb;
        unsigned int* dst = (unsigned int*)Hbf;
        unsigned int v[32];
        #pragma unroll
        for (int c2 = 0; c2 < 32; c2++)
            v[c2] = src[base2 + ((size_t)c2 << 13) + e2];
        float s0f = 0.f, s1f = 0.f;
        #pragma unroll
        for (int c2 = 0; c2 < 32; c2++) {
            union { u16 u[2]; unsigned int q; } pk;
            pk.u[0] = f2h(s0f); pk.u[1] = f2h(s1f);
            dst[base2 + ((size_t)c2 << 13) + e2] = pk.q;
            float d = sdec[c2];
            s0f = d * s0f + h2f((u16)(v[c2] & 0xffffu));
            s1f = d * s1f + h2f((u16)(v[c2] >> 16));
        }
    }
    cg::this_grid().sync();
    // ---- phase C1: Y = Ctok @ Hin^T (Hin fragments straight from global)
    f32x4 acc[2][4];
    #pragma unroll
    for (int i = 0; i < 2; i++)
        #pragma unroll
        for (int j = 0; j < 4; j++) acc[i][j] = f32x4{0.f, 0.f, 0.f, 0.f};
    {
        const u16* hg = Hbf + blk;
        #pragma unroll
        for (int ks = 0; ks < 4; ks++) {
            f16x8 ca[2], hb[4];
            int kc = ks * 4 + quad;
            #pragma unroll
            for (int i = 0; i < 2; i++) {
                int r = wm + i * 16 + cl;
                ca[i] = *(const f16x8*)&Ctok[r * 128 + ((kc ^ (r & 15)) << 3)];
            }
            #pragma unroll
            for (int j = 0; j < 4; j++) {
                int r = wn + j * 16 + cl;
                hb[j] = *(const f16x8*)(hg + (size_t)r * 128 + kc * 8);
            }
            #pragma unroll
            for (int i = 0; i < 2; i++)
                #pragma unroll
                for (int j = 0; j < 4; j++)
                    acc[i][j] = __builtin_amdgcn_mfma_f32_16x16x32_f16(
                        ca[i], hb[j], acc[i][j], 0, 0, 0);
        }
    }
    #pragma unroll
    for (int i = 0; i < 2; i++)
        #pragma unroll
        for (int r = 0; r < 4; r++) {
            float e = __expf(sS[wm + i * 16 + quad * 4 + r]);
            #pragma unroll
            for (int j = 0; j < 4; j++) acc[i][j][r] *= e;
        }
    // ---- phase C2: S = Ctok @ Btok^T (triangular skip)
    f32x4 sacc[2][4];
    #pragma unroll
    for (int i = 0; i < 2; i++)
        #pragma unroll
        for (int j = 0; j < 4; j++) sacc[i][j] = f32x4{0.f, 0.f, 0.f, 0.f};
    #pragma unroll
    for (int ks = 0; ks < 4; ks++) {
        f16x8 cs[2], bs[4];
        int kc = ks * 4 + quad;
        #pragma unroll
        for (int i2 = 0; i2 < 2; i2++) {
            int r = wm + i2 * 16 + cl;
            cs[i2] = *(const f16x8*)&Ctok[r * 128 + ((kc ^ (r & 15)) << 3)];
        }
        #pragma unroll
        for (int j = 0; j < 4; j++) {
            int r = wn + j * 16 + cl;
            bs[j] = *(const f16x8*)&Btok[r * 128 + ((kc ^ (r & 15)) << 3)];
        }
        #pragma unroll
        for (int i2 = 0; i2 < 2; i2++)
            #pragma unroll
            for (int j = 0; j < 4; j++)
                if (wm + i2 * 16 + 15 >= wn + j * 16)
                    sacc[i2][j] = __builtin_amdgcn_mfma_f32_16x16x32_f16(
                        cs[i2], bs[j], sacc[i2][j], 0, 0, 0);
    }
    // ---- G = mask ∘ S ∘ exp(St-Ss) ∘ dt_s  -> BTw (dead since phase A)
    #pragma unroll
    for (int i2 = 0; i2 < 2; i2++)
        #pragma unroll
        for (int r = 0; r < 4; r++) {
            int t = wm + i2 * 16 + quad * 4 + r;
            float Stv = sS[t];
            #pragma unroll
            for (int j = 0; j < 4; j++) {
                int s = wn + j * 16 + cl;
                float gv = 0.f;
                if (s <= t) gv = sacc[i2][j][r] * __expf(Stv - sS[s]) * sdt[s];
                BTw[t * 128 + (((s >> 3) ^ (t & 15)) << 3) + (s & 7)] = f2h(gv);
            }
        }
    __syncthreads();
    // ---- phase C3: Y += G @ X
    #pragma unroll
    for (int ks = 0; ks < 4; ks++) {
        f16x8 ga[2], xb[4];
        int kc = ks * 4 + quad;
        #pragma unroll
        for (int i = 0; i < 2; i++) {
            int r = wm + i * 16 + cl;
            ga[i] = *(const f16x8*)&BTw[r * 128 + ((kc ^ (r & 15)) << 3)];
        }
        #pragma unroll
        for (int j = 0; j < 4; j++) {
            int r = wn + j * 16 + cl;
            xb[j] = *(const f16x8*)&XT[r * 128 + ((kc ^ (r & 15)) << 3)];
        }
        #pragma unroll
        for (int i = 0; i < 2; i++)
            #pragma unroll
            for (int j = 0; j < 4; j++)
                acc[i][j] = __builtin_amdgcn_mfma_f32_16x16x32_f16(
                    ga[i], xb[j], acc[i][j], 0, 0, 0);
    }
    // ---- epilogue: g = (Y + D*x)*silu(z)
    const float dco = Dp[h];
    #pragma unroll
    for (int i = 0; i < 2; i++)
        #pragma unroll
        for (int r = 0; r < 4; r++) {
            int t = wm + i * 16 + quad * 4 + r;
            u16* row = g16 + (size_t)(tok0 + t) * 256 + h * 128;
            #pragma unroll
            for (int j = 0; j < 4; j++) {
                int p = wn + j * 16 + cl;
                float xv = h2f(XT[p * 128 + (((t >> 3) ^ (p & 15)) << 3) + (t & 7)]);
                float zv = h2f(zx16[(size_t)(tok0 + t) * 768 + h * 128 + p]);
                row[p] = f2h((acc[i][j][r] + dco * xv) * silu_f(zv));
            }
        }
}

// ---------------------------------------------------------------------------
// out-proj GEMM (K=256, N=128, BM=64) + residual + RMS (+ fused final
// projection in mode 3). (unchanged)
// ---------------------------------------------------------------------------
__global__ __launch_bounds__(256) void gemm_outrms_kernel(
    const u16* __restrict__ A, const float* __restrict__ Wf,
    const float* __restrict__ gnw, const float* __restrict__ rmsw,
    u16* __restrict__ xp16, u16* __restrict__ hbuf16, u16* __restrict__ hn16,
    const float* __restrict__ out_wf, const float* __restrict__ out_b,
    float* __restrict__ dout, int mode)
{
    __shared__ u16 sA[64 * 64];
    __shared__ u16 sW[128 * 64];
    __shared__ float red[64][33];
    __shared__ float srstd[64];
    __shared__ float redp[64][5];
    __shared__ float rstdg[64];
    __shared__ u16 hn2[64 * 128];
    __shared__ u16 ow[64 * 128];
    const int K = 256;
    const int m0 = blockIdx.y * 64;
    const int tid = threadIdx.x, wid = tid >> 6, lane = tid & 63;
    const int wm = (wid >> 1) * 32, wn = (wid & 1) * 64;
    const int quad = lane >> 4, cl = lane & 15;
    f32x4 acc[2][4];
    #pragma unroll
    for (int i = 0; i < 2; i++)
        #pragma unroll
        for (int j = 0; j < 4; j++) acc[i][j] = f32x4{0.f, 0.f, 0.f, 0.f};

    float ssq = 0.f;
    for (int k0 = 0; k0 < K; k0 += 64) {
        #pragma unroll
        for (int i = 0; i < 2; i++) {
            int ck = i * 256 + tid;
            int r = ck >> 3, cc = ck & 7;
            int csw = (cc ^ (r & 7)) << 3;
            async_lds16(A + (size_t)(m0 + r) * K + k0 + csw,
                        (void*)(sA + (i * 256 + (tid & ~63)) * 8));
        }
        #pragma unroll
        for (int i = 0; i < 4; i++) {
            int ck = i * 256 + tid;
            int r = ck >> 3, cc = ck & 7;
            int csw = (cc ^ (r & 7)) << 3;
            *(uint4*)&sW[ck * 8] = cvt8g(Wf + (size_t)r * K + k0 + csw,
                                         gnw + k0 + csw);
        }
        __syncthreads();
        {
            int rr = tid >> 2, q = tid & 3;
            f16x8 v0 = *(const f16x8*)&sA[rr * 64 + q * 16];
            f16x8 v1 = *(const f16x8*)&sA[rr * 64 + q * 16 + 8];
            #pragma unroll
            for (int j = 0; j < 8; j++) {
                float a = (float)v0[j], bq = (float)v1[j];
                ssq += a * a + bq * bq;
            }
        }
        #pragma unroll
        for (int ks = 0; ks < 2; ks++) {
            f16x8 af[2], wv[4];
            int kc = ks * 4 + quad;
            #pragma unroll
            for (int i = 0; i < 2; i++) {
                int r = wm + i * 16 + cl;
                af[i] = *(const f16x8*)&sA[r * 64 + ((kc ^ (r & 7)) << 3)];
            }
            #pragma unroll
            for (int j = 0; j < 4; j++) {
                int r = wn + j * 16 + cl;
                wv[j] = *(const f16x8*)&sW[r * 64 + ((kc ^ (r & 7)) << 3)];
            }
            #pragma unroll
            for (int i = 0; i < 2; i++)
                #pragma unroll
                for (int j = 0; j < 4; j++)
                    acc[i][j] = __builtin_amdgcn_mfma_f32_16x16x32_f16(
                        af[i], wv[j], acc[i][j], 0, 0, 0);
        }
        __syncthreads();
    }
    redp[tid >> 2][tid & 3] = ssq;
    __syncthreads();
    if (tid < 64)
        rstdg[tid] = rsqrtf((redp[tid][0] + redp[tid][1] + redp[tid][2]
                             + redp[tid][3]) * (1.f / 256.f) + 1e-5f);
    __syncthreads();
    const int slot = (wid & 1) * 16 + cl;
    #pragma unroll
    for (int i = 0; i < 2; i++)
        #pragma unroll
        for (int r = 0; r < 4; r++) {
            int t = wm + i * 16 + quad * 4 + r;
            size_t ob = (size_t)(m0 + t) * 128;
            float rg = rstdg[t];
            float ssp = 0.f;
            #pragma unroll
            for (int j = 0; j < 4; j++) {
                int n = wn + j * 16 + cl;
                float v = acc[i][j][r] * rg + h2f(hbuf16[ob + n]);
                acc[i][j][r] = v;
                ssp += v * v;
            }
            red[t][slot] = ssp;
        }
    __syncthreads();
    if (tid < 64) {
        float s = 0.f;
        #pragma unroll
        for (int sl = 0; sl < 32; sl++) s += red[tid][sl];
        srstd[tid] = rsqrtf(s * (1.f / 128.f) + 1e-5f);
    }
    __syncthreads();
    #pragma unroll
    for (int i = 0; i < 2; i++)
        #pragma unroll
        for (int r = 0; r < 4; r++) {
            int t = wm + i * 16 + quad * 4 + r;
            size_t ob = (size_t)(m0 + t) * 128;
            float rstd = srstd[t];
            #pragma unroll
            for (int j = 0; j < 4; j++) {
                int n = wn + j * 16 + cl;
                float v = acc[i][j][r];
                float val = v * rstd * rmsw[n];
                if (mode == 1) {
                    hbuf16[ob + n] = f2h(v);
                    hn16[ob + n] = f2h(val);
                } else {
                    val += h2f(xp16[ob + n]);
                    hn2[t * 128 + (((n >> 3) ^ (t & 15)) << 3) + (n & 7)] = f2h(val);
                }
            }
        }
    if (mode == 1) return;
    #pragma unroll
    for (int i = 0; i < 4; i++) {
        int ck = i * 256 + tid;
        int rr = ck >> 4, cc = ck & 15;
        int csw = (cc ^ (rr & 15)) << 3;
        *(uint4*)&ow[ck * 8] = cvt8(out_wf + (size_t)rr * 128 + csw);
    }
    __syncthreads();
    const int wm4 = (wid >> 1) * 32, wn4 = (wid & 1) * 32;
    f32x4 acc2[2][2];
    #pragma unroll
    for (int i = 0; i < 2; i++)
        #pragma unroll
        for (int j = 0; j < 2; j++) acc2[i][j] = f32x4{0.f, 0.f, 0.f, 0.f};
    #pragma unroll
    for (int ks = 0; ks < 4; ks++) {
        f16x8 af2[2], wf2[2];
        int kc = ks * 4 + quad;
        #pragma unroll
        for (int i = 0; i < 2; i++) {
            int r = wm4 + i * 16 + cl;
            af2[i] = *(const f16x8*)&hn2[r * 128 + ((kc ^ (r & 15)) << 3)];
        }
        #pragma unroll
        for (int j = 0; j < 2; j++) {
            int rr = wn4 + j * 16 + cl;
            wf2[j] = *(const f16x8*)&ow[rr * 128 + ((kc ^ (rr & 15)) << 3)];
        }
        #pragma unroll
        for (int i = 0; i < 2; i++)
            #pragma unroll
            for (int j = 0; j < 2; j++)
                acc2[i][j] = __builtin_amdgcn_mfma_f32_16x16x32_f16(
                    af2[i], wf2[j], acc2[i][j], 0, 0, 0);
    }
    #pragma unroll
    for (int i = 0; i < 2; i++) {
        int m = m0 + wm4 + i * 16 + quad * 4;
        #pragma unroll
        for (int j = 0; j < 2; j++) {
            int n = wn4 + j * 16 + cl;
            float bv = out_b[n];
            #pragma unroll
            for (int r = 0; r < 4; r++)
                dout[(size_t)(m + r) * 64 + n] = acc2[i][j][r] + bv;
        }
    }
}

// ---------------------------------------------------------------------------
extern "C" void kernel_launch(void* const* d_in, const int* in_sizes, int n_in,
                              void* d_out, int out_size, void* d_ws, size_t ws_size,
                              hipStream_t stream)
{
    (void)in_sizes; (void)n_in; (void)out_size; (void)ws_size;
    const float* x       = (const float*)d_in[0];
    const float* in_w    = (const float*)d_in[1];
    const float* in_b    = (const float*)d_in[2];
    const float* out_w   = (const float*)d_in[3];
    const float* out_b   = (const float*)d_in[4];
    const float* l_rms_w = (const float*)d_in[5];
    const float* l_in_w  = (const float*)d_in[6];
    const float* conv_w  = (const float*)d_in[7];
    const float* conv_b  = (const float*)d_in[8];
    const float* dt_bias = (const float*)d_in[9];
    const float* A_log   = (const float*)d_in[10];
    const float* D_p     = (const float*)d_in[11];
    const float* gnorm_w = (const float*)d_in[12];
    const float* l_out_w = (const float*)d_in[13];
    const float* fnorm_w = (const float*)d_in[14];

    char* w = (char*)d_ws;
    u16*   xp16   = (u16*)(w);                  // 4.19 MB
    u16*   hbuf16 = (u16*)(w + 4194304);        // 4.19 MB
    u16*   hn16   = (u16*)(w + 8388608);        // 4.19 MB
    u16*   zx16   = (u16*)(w + 12582912);       // 25.17 MB
    float* dtb    = (float*)(w + 37748736);     // 131 KB
    float* Sb     = (float*)(w + 37879808);     // 131 KB
    u16*   Hb     = (u16*)(w + 38010880);       // 8.39 MB
    u16*   Hbf    = (u16*)(w + 46399488);       // 8.39 MB
    u16*   g16    = (u16*)(w + 54788096);       // 8.39 MB

    gemm_rms0_kernel<<<dim3(1, 256), 256, 0, stream>>>(
        x, in_w, in_b, l_rms_w, xp16, hbuf16, hn16);

    for (int i = 0; i < 2; i++) {
        gemm_inproj_kernel<<<dim3(7, 128), 256, 0, stream>>>(
            hn16, l_in_w + (size_t)i * 770 * 128, zx16, dtb, Sb,
            dt_bias + i * 2, A_log + i * 2);
        {
            const u16* zxp = zx16;
            const float* cwp = conv_w + i * 2048;
            const float* cbp = conv_b + i * 512;
            const float* dtbp = dtb;
            const float* Sbp = Sb;
            u16* Hbp = Hb;
            u16* Hbfp = Hbf;
            const float* Dpp = D_p + i * 2;
            u16* g16p = g16;
            void* fargs[9] = { (void*)&zxp, (void*)&cwp, (void*)&cbp,
                               (void*)&dtbp, (void*)&Sbp, (void*)&Hbp,
                               (void*)&Hbfp, (void*)&Dpp, (void*)&g16p };
            hipLaunchCooperativeKernel((void*)fused_mamba_kernel,
                                       dim3(32, 2, 4), dim3(512),
                                       fargs, 0, stream);
        }
        gemm_outrms_kernel<<<dim3(1, 256), 256, 0, stream>>>(
            g16, l_out_w + (size_t)i * 128 * 256, gnorm_w + i * 256,
            (i == 0) ? (l_rms_w + 128) : fnorm_w, xp16, hbuf16, hn16,
            out_w, out_b, (float*)d_out, (i == 0) ? 1 : 3);
    }
}

// Round 3
// 292.253 us; speedup vs baseline: 1.3749x; 1.3749x over previous
//
#include <hip/hip_runtime.h>
#include <cstddef>
#include <cstdint>

// MambaDoc — round 16: exact R13 structure (226.07 µs verified) + two deltas:
//  (1) boundary zero-fix folded into conv reads as a per-lane select
//      (removes sync;zero;sync pairs: ssd -3 barriers, chunkstate -2);
//  (2) ssd phase C1 reads Hin fragments directly from global (validated in
//      R15's fused kernel) — deletes the Hin staging round (-2 barriers).
// Cooperative fusion (R15) reverted: grid.sync cost ~40 µs/dispatch.

#define LSEQ 4096
#define MTOK 16384

typedef unsigned short u16;
typedef _Float16 f16x8 __attribute__((ext_vector_type(8)));
typedef float f32x4 __attribute__((ext_vector_type(4)));

__device__ __forceinline__ u16 f2h(float x) {
    return __builtin_bit_cast(u16, (_Float16)x);
}
__device__ __forceinline__ float h2f(u16 u) {
    return (float)__builtin_bit_cast(_Float16, u);
}
__device__ __forceinline__ float silu_f(float x) { return x / (1.f + __expf(-x)); }

__device__ __forceinline__ void async_lds16(const void* g, void* l) {
    __builtin_amdgcn_global_load_lds(
        (const __attribute__((address_space(1))) unsigned int*)g,
        (__attribute__((address_space(3))) unsigned int*)l, 16, 0, 0);
}

__device__ __forceinline__ uint4 cvt8(const float* __restrict__ src) {
    float4 a = *(const float4*)src;
    float4 b = *(const float4*)(src + 4);
    union { u16 u[8]; uint4 q; } pk;
    pk.u[0] = f2h(a.x); pk.u[1] = f2h(a.y); pk.u[2] = f2h(a.z); pk.u[3] = f2h(a.w);
    pk.u[4] = f2h(b.x); pk.u[5] = f2h(b.y); pk.u[6] = f2h(b.z); pk.u[7] = f2h(b.w);
    return pk.q;
}

__device__ __forceinline__ uint4 cvt8g(const float* __restrict__ src,
                                       const float* __restrict__ gw) {
    float4 a = *(const float4*)src;
    float4 b = *(const float4*)(src + 4);
    float4 ga = *(const float4*)gw;
    float4 gb = *(const float4*)(gw + 4);
    union { u16 u[8]; uint4 q; } pk;
    pk.u[0] = f2h(a.x * ga.x); pk.u[1] = f2h(a.y * ga.y);
    pk.u[2] = f2h(a.z * ga.z); pk.u[3] = f2h(a.w * ga.w);
    pk.u[4] = f2h(b.x * gb.x); pk.u[5] = f2h(b.y * gb.y);
    pk.u[6] = f2h(b.z * gb.z); pk.u[7] = f2h(b.w * gb.w);
    return pk.q;
}

// ---------------------------------------------------------------------------
// Initial projection + fused RMSNorm. BM=64, grid (1,256). (unchanged)
// ---------------------------------------------------------------------------
__global__ __launch_bounds__(256) void gemm_rms0_kernel(
    const float* __restrict__ xf, const float* __restrict__ wf,
    const float* __restrict__ bias, const float* __restrict__ rmsw,
    u16* __restrict__ xp16, u16* __restrict__ hbuf16, u16* __restrict__ hn16)
{
    __shared__ u16 sA[64 * 64];
    __shared__ u16 sW[128 * 64];
    __shared__ float red[64][33];
    __shared__ float srstd[64];
    const int m0 = blockIdx.y * 64;
    const int tid = threadIdx.x, wid = tid >> 6, lane = tid & 63;
    const int wm = (wid >> 1) * 32, wn = (wid & 1) * 64;
    const int quad = lane >> 4, cl = lane & 15;
    #pragma unroll
    for (int i = 0; i < 2; i++) {
        int ck = i * 256 + tid;
        int r = ck >> 3, cc = ck & 7;
        int csw = (cc ^ (r & 7)) << 3;
        *(uint4*)&sA[ck * 8] = cvt8(xf + (size_t)(m0 + r) * 64 + csw);
    }
    #pragma unroll
    for (int i = 0; i < 4; i++) {
        int ck = i * 256 + tid;
        int r = ck >> 3, cc = ck & 7;
        int csw = (cc ^ (r & 7)) << 3;
        *(uint4*)&sW[ck * 8] = cvt8(wf + (size_t)r * 64 + csw);
    }
    __syncthreads();
    f32x4 acc[2][4];
    #pragma unroll
    for (int i = 0; i < 2; i++)
        #pragma unroll
        for (int j = 0; j < 4; j++) acc[i][j] = f32x4{0.f, 0.f, 0.f, 0.f};
    #pragma unroll
    for (int ks = 0; ks < 2; ks++) {
        f16x8 af[2], wv[4];
        int kc = ks * 4 + quad;
        #pragma unroll
        for (int i = 0; i < 2; i++) {
            int r = wm + i * 16 + cl;
            af[i] = *(const f16x8*)&sA[r * 64 + ((kc ^ (r & 7)) << 3)];
        }
        #pragma unroll
        for (int j = 0; j < 4; j++) {
            int r = wn + j * 16 + cl;
            wv[j] = *(const f16x8*)&sW[r * 64 + ((kc ^ (r & 7)) << 3)];
        }
        #pragma unroll
        for (int i = 0; i < 2; i++)
            #pragma unroll
            for (int j = 0; j < 4; j++)
                acc[i][j] = __builtin_amdgcn_mfma_f32_16x16x32_f16(
                    af[i], wv[j], acc[i][j], 0, 0, 0);
    }
    const int slot = (wid & 1) * 16 + cl;
    #pragma unroll
    for (int i = 0; i < 2; i++)
        #pragma unroll
        for (int r = 0; r < 4; r++) {
            int t = wm + i * 16 + quad * 4 + r;
            float ssp = 0.f;
            #pragma unroll
            for (int j = 0; j < 4; j++) {
                int n = wn + j * 16 + cl;
                float v = acc[i][j][r] + bias[n];
                acc[i][j][r] = v;
                ssp += v * v;
            }
            red[t][slot] = ssp;
        }
    __syncthreads();
    if (tid < 64) {
        float s = 0.f;
        #pragma unroll
        for (int sl = 0; sl < 32; sl++) s += red[tid][sl];
        srstd[tid] = rsqrtf(s * (1.f / 128.f) + 1e-5f);
    }
    __syncthreads();
    #pragma unroll
    for (int i = 0; i < 2; i++)
        #pragma unroll
        for (int r = 0; r < 4; r++) {
            int t = wm + i * 16 + quad * 4 + r;
            size_t ob = (size_t)(m0 + t) * 128;
            float rstd = srstd[t];
            #pragma unroll
            for (int j = 0; j < 4; j++) {
                int n = wn + j * 16 + cl;
                float v = acc[i][j][r];
                u16 vh = f2h(v);
                xp16[ob + n] = vh;
                hbuf16[ob + n] = vh;
                hn16[ob + n] = f2h(v * rstd * rmsw[n]);
            }
        }
}

// ---------------------------------------------------------------------------
// in_proj GEMM fp16 (K=128). Grid (7, 128). (unchanged)
// ---------------------------------------------------------------------------
__global__ __launch_bounds__(256) void gemm_inproj_kernel(
    const u16* __restrict__ A, const float* __restrict__ Wf,
    u16* __restrict__ zx16, float* __restrict__ dtb, float* __restrict__ Sb,
    const float* __restrict__ dt_bias, const float* __restrict__ A_log)
{
    __shared__ u16 sA[128 * 64];
    __shared__ u16 sW[128 * 64];
    __shared__ float sdt[2][128];
    const int K = 128, N = 770;
    const int n0 = blockIdx.x * 128, m0 = blockIdx.y * 128;
    const int tid = threadIdx.x, wid = tid >> 6, lane = tid & 63;
    const int wm = (wid >> 1) * 64, wn = (wid & 1) * 64;
    const int quad = lane >> 4, cl = lane & 15;
    f32x4 acc[4][4];
    #pragma unroll
    for (int i = 0; i < 4; i++)
        #pragma unroll
        for (int j = 0; j < 4; j++) acc[i][j] = f32x4{0.f, 0.f, 0.f, 0.f};

    for (int k0 = 0; k0 < K; k0 += 64) {
        #pragma unroll
        for (int i = 0; i < 4; i++) {
            int ck = i * 256 + tid;
            int r = ck >> 3, cc = ck & 7;
            int csw = (cc ^ (r & 7)) << 3;
            async_lds16(A + (size_t)(m0 + r) * K + k0 + csw,
                        (void*)(sA + (i * 256 + (tid & ~63)) * 8));
        }
        #pragma unroll
        for (int i = 0; i < 4; i++) {
            int ck = i * 256 + tid;
            int r = ck >> 3, cc = ck & 7;
            int csw = (cc ^ (r & 7)) << 3;
            int rr = n0 + r; if (rr >= N) rr = N - 1;
            *(uint4*)&sW[ck * 8] = cvt8(Wf + (size_t)rr * K + k0 + csw);
        }
        __syncthreads();
        #pragma unroll
        for (int ks = 0; ks < 2; ks++) {
            f16x8 af[4], wv[4];
            int kc = ks * 4 + quad;
            #pragma unroll
            for (int i = 0; i < 4; i++) {
                int r = wm + i * 16 + cl;
                af[i] = *(const f16x8*)&sA[r * 64 + ((kc ^ (r & 7)) << 3)];
            }
            #pragma unroll
            for (int j = 0; j < 4; j++) {
                int r = wn + j * 16 + cl;
                wv[j] = *(const f16x8*)&sW[r * 64 + ((kc ^ (r & 7)) << 3)];
            }
            #pragma unroll
            for (int i = 0; i < 4; i++)
                #pragma unroll
                for (int j = 0; j < 4; j++)
                    acc[i][j] = __builtin_amdgcn_mfma_f32_16x16x32_f16(
                        af[i], wv[j], acc[i][j], 0, 0, 0);
        }
        __syncthreads();
    }
    if (blockIdx.x < 6) {
        #pragma unroll
        for (int i = 0; i < 4; i++) {
            int m = m0 + wm + i * 16 + quad * 4;
            #pragma unroll
            for (int j = 0; j < 4; j++) {
                int n = n0 + wn + j * 16 + cl;
                #pragma unroll
                for (int r = 0; r < 4; r++)
                    zx16[(size_t)(m + r) * 768 + n] = f2h(acc[i][j][r]);
            }
        }
    } else {
        if ((wid & 1) == 0 && cl < 2) {
            #pragma unroll
            for (int i = 0; i < 4; i++)
                #pragma unroll
                for (int r = 0; r < 4; r++)
                    sdt[cl][wm + i * 16 + quad * 4 + r] = acc[i][0][r];
        }
        __syncthreads();
        const int hh = tid >> 7, t = tid & 127;
        float raw = sdt[hh][t] + dt_bias[hh];
        float dt = fmaxf(raw, 0.f) + log1pf(__expf(-fabsf(raw)));
        dtb[(size_t)(m0 + t) * 2 + hh] = dt;
        float ad = -__expf(A_log[hh]) * dt;
        __syncthreads();
        sdt[hh][t] = ad;
        __syncthreads();
        for (int off = 1; off < 128; off <<= 1) {
            float add = (t >= off) ? sdt[hh][t - off] : 0.f;
            __syncthreads();
            sdt[hh][t] += add;
            __syncthreads();
        }
        Sb[(size_t)(m0 + t) * 2 + hh] = sdt[hh][t];
    }
}

// ---------------------------------------------------------------------------
// chunkstate + inlined conv. Grid (32,2,4), 512 thr.
// R16: zero-fix folded into conv reads (barriers 6 -> 4).
// ---------------------------------------------------------------------------
__global__ __launch_bounds__(512) void chunkstate_conv_kernel(
    const u16* __restrict__ zx16, const float* __restrict__ cw,
    const float* __restrict__ cb, const float* __restrict__ dtb,
    const float* __restrict__ Sb, u16* __restrict__ Hb)
{
    __shared__ u16 raw[2560 * 8];
    __shared__ u16 XT[128 * 128];
    __shared__ u16 BT[128 * 128];
    __shared__ float scw[2][128][4];
    __shared__ float scb[2][128];
    __shared__ float ssw[128];
    const int c = blockIdx.x, h = blockIdx.y, b = blockIdx.z;
    const int tid = threadIdx.x, wid = tid >> 6, lane = tid & 63;
    const int quad = lane >> 4, cl = lane & 15;
    const int tok0 = b * LSEQ + c * 128;
    for (int idx = tid; idx < 256; idx += 512) {
        int grp = idx >> 7, j = idx & 127;
        int ch = grp ? (256 + j) : (128 * h + j);
        float4 w4 = *(const float4*)&cw[ch * 4];
        scw[grp][j][0] = w4.x; scw[grp][j][1] = w4.y;
        scw[grp][j][2] = w4.z; scw[grp][j][3] = w4.w;
        scb[grp][j] = cb[ch];
    }
    if (tid < 128) {
        float Sl = Sb[(size_t)(tok0 + 127) * 2 + h];
        ssw[tid] = __expf(Sl - Sb[(size_t)(tok0 + tid) * 2 + h])
                   * dtb[(size_t)(tok0 + tid) * 2 + h];
    }
    #pragma unroll
    for (int i = 0; i < 5; i++) {
        int ck = i * 512 + tid;
        int r = ck >> 4; if (r > 130) r = 130;
        int cc = ck & 15;
        int tok = tok0 - 3 + r; if (tok < 0) tok = 0;
        async_lds16(zx16 + (size_t)tok * 768 + 256 + 128 * h + ((cc ^ (r & 15)) << 3),
                    (void*)(raw + (i * 512 + (tid & ~63)) * 8));
    }
    __syncthreads();
    #pragma unroll
    for (int it = 0; it < 4; it++) {
        int idx = it * 512 + tid;
        int s = idx & 127, pg = idx >> 7;
        f16x8 v[4];
        #pragma unroll
        for (int k = 0; k < 4; k++) {
            int rr = s + k;
            uint4 u = *(const uint4*)&raw[rr * 128 + ((pg ^ (rr & 15)) << 3)];
            if (c == 0 && rr < 3) u = make_uint4(0u, 0u, 0u, 0u);
            v[k] = __builtin_bit_cast(f16x8, u);
        }
        #pragma unroll
        for (int j = 0; j < 8; j++) {
            int p = pg * 8 + j;
            float o = scb[0][p] + (float)v[0][j] * scw[0][p][0]
                    + (float)v[1][j] * scw[0][p][1]
                    + (float)v[2][j] * scw[0][p][2]
                    + (float)v[3][j] * scw[0][p][3];
            o = silu_f(o);
            XT[p * 128 + (((s >> 3) ^ (p & 15)) << 3) + (s & 7)] = f2h(o);
        }
    }
    __syncthreads();
    #pragma unroll
    for (int i = 0; i < 5; i++) {
        int ck = i * 512 + tid;
        int r = ck >> 4; if (r > 130) r = 130;
        int cc = ck & 15;
        int tok = tok0 - 3 + r; if (tok < 0) tok = 0;
        async_lds16(zx16 + (size_t)tok * 768 + 512 + ((cc ^ (r & 15)) << 3),
                    (void*)(raw + (i * 512 + (tid & ~63)) * 8));
    }
    __syncthreads();
    #pragma unroll
    for (int it = 0; it < 4; it++) {
        int idx = it * 512 + tid;
        int s = idx & 127, ng = idx >> 7;
        f16x8 v[4];
        #pragma unroll
        for (int k = 0; k < 4; k++) {
            int rr = s + k;
            uint4 u = *(const uint4*)&raw[rr * 128 + ((ng ^ (rr & 15)) << 3)];
            if (c == 0 && rr < 3) u = make_uint4(0u, 0u, 0u, 0u);
            v[k] = __builtin_bit_cast(f16x8, u);
        }
        float wsv = ssw[s];
        #pragma unroll
        for (int j = 0; j < 8; j++) {
            int n = ng * 8 + j;
            float o = scb[1][n] + (float)v[0][j] * scw[1][n][0]
                    + (float)v[1][j] * scw[1][n][1]
                    + (float)v[2][j] * scw[1][n][2]
                    + (float)v[3][j] * scw[1][n][3];
            o = silu_f(o) * wsv;
            BT[n * 128 + (((s >> 3) ^ (n & 15)) << 3) + (s & 7)] = f2h(o);
        }
    }
    __syncthreads();
    const size_t blk = ((size_t)((b * 2 + h) * 32 + c)) << 14;
    const int wm = (wid >> 1) * 32, wn = (wid & 1) * 64;
    f32x4 acc[2][4];
    #pragma unroll
    for (int i = 0; i < 2; i++)
        #pragma unroll
        for (int j = 0; j < 4; j++) acc[i][j] = f32x4{0.f, 0.f, 0.f, 0.f};
    #pragma unroll
    for (int ks = 0; ks < 4; ks++) {
        f16x8 xa[2], bb[4];
        int kc = ks * 4 + quad;
        #pragma unroll
        for (int i = 0; i < 2; i++) {
            int r = wm + i * 16 + cl;
            xa[i] = *(const f16x8*)&XT[r * 128 + ((kc ^ (r & 15)) << 3)];
        }
        #pragma unroll
        for (int j = 0; j < 4; j++) {
            int r = wn + j * 16 + cl;
            bb[j] = *(const f16x8*)&BT[r * 128 + ((kc ^ (r & 15)) << 3)];
        }
        #pragma unroll
        for (int i = 0; i < 2; i++)
            #pragma unroll
            for (int j = 0; j < 4; j++)
                acc[i][j] = __builtin_amdgcn_mfma_f32_16x16x32_f16(
                    xa[i], bb[j], acc[i][j], 0, 0, 0);
    }
    u16* out = Hb + blk;
    #pragma unroll
    for (int i = 0; i < 2; i++)
        #pragma unroll
        for (int j = 0; j < 4; j++)
            #pragma unroll
            for (int r = 0; r < 4; r++)
                out[(size_t)(wm + i * 16 + quad * 4 + r) * 128 + wn + j * 16 + cl]
                    = f2h(acc[i][j][r]);
}

// ---------------------------------------------------------------------------
// Inter-chunk combine — register-prefetch. Grid (32,2,4), 256 thr. (unchanged)
// ---------------------------------------------------------------------------
__global__ __launch_bounds__(256) void statecombine_kernel(
    const float* __restrict__ Sb, const u16* __restrict__ Hb,
    u16* __restrict__ Hbf)
{
    __shared__ float sdec[32];
    const int h = blockIdx.y, b = blockIdx.z;
    const int e2 = blockIdx.x * 256 + threadIdx.x;
    if (threadIdx.x < 32)
        sdec[threadIdx.x] =
            __expf(Sb[(size_t)(b * LSEQ + threadIdx.x * 128 + 127) * 2 + h]);
    const size_t base2 = ((size_t)((b * 2 + h) * 32)) << 13;
    const unsigned int* src = (const unsigned int*)Hb;
    unsigned int* dst = (unsigned int*)Hbf;
    unsigned int v[32];
    #pragma unroll
    for (int c = 0; c < 32; c++)
        v[c] = src[base2 + ((size_t)c << 13) + e2];
    __syncthreads();
    float s0 = 0.f, s1 = 0.f;
    #pragma unroll
    for (int c = 0; c < 32; c++) {
        union { u16 u[2]; unsigned int q; } pk;
        pk.u[0] = f2h(s0); pk.u[1] = f2h(s1);
        dst[base2 + ((size_t)c << 13) + e2] = pk.q;
        float d = sdec[c];
        s0 = d * s0 + h2f((u16)(v[c] & 0xffffu));
        s1 = d * s1 + h2f((u16)(v[c] >> 16));
    }
}

// ---------------------------------------------------------------------------
// Per-head fused SSD. Grid (32,2,4), 512 thr.
// R16: zero-fix folded into conv reads; Hin read direct from global in C1
// (no LDS staging). Barriers 13 -> 7.
// ---------------------------------------------------------------------------
__global__ __launch_bounds__(512) void ssd_ph_kernel(
    const u16* __restrict__ zx16, const u16* __restrict__ Hbf,
    const float* __restrict__ dtb, const float* __restrict__ Sb,
    const float* __restrict__ cw, const float* __restrict__ cb,
    const float* __restrict__ Dp, u16* __restrict__ g16)
{
    __shared__ u16 raw[2560 * 8];     // staging X/B/C -> later G
    __shared__ u16 XT[128 * 128];
    __shared__ u16 Btok[128 * 128];
    __shared__ u16 Ctok[128 * 128];
    __shared__ float sS[128], sdt[128];
    __shared__ float scw[3][128][4];
    __shared__ float scb[3][128];
    const int c = blockIdx.x, h = blockIdx.y, b = blockIdx.z;
    const int tid = threadIdx.x, wid = tid >> 6, lane = tid & 63;
    const int quad = lane >> 4, cl = lane & 15;
    const int tok0 = b * LSEQ + c * 128;
    const size_t blk = ((size_t)((b * 2 + h) * 32 + c)) << 14;
    for (int idx = tid; idx < 384; idx += 512) {
        int grp = idx >> 7, j = idx & 127;
        int ch = (grp == 0) ? (128 * h + j) : (grp == 1 ? 256 + j : 384 + j);
        float4 w4 = *(const float4*)&cw[ch * 4];
        scw[grp][j][0] = w4.x; scw[grp][j][1] = w4.y;
        scw[grp][j][2] = w4.z; scw[grp][j][3] = w4.w;
        scb[grp][j] = cb[ch];
    }
    if (tid < 128) {
        sS[tid] = Sb[(size_t)(tok0 + tid) * 2 + h];
        sdt[tid] = dtb[(size_t)(tok0 + tid) * 2 + h];
    }
    // ---- conv X -> XT
    #pragma unroll
    for (int i = 0; i < 5; i++) {
        int ck = i * 512 + tid;
        int r = ck >> 4; if (r > 130) r = 130;
        int cc = ck & 15;
        int tok = tok0 - 3 + r; if (tok < 0) tok = 0;
        async_lds16(zx16 + (size_t)tok * 768 + 256 + 128 * h + ((cc ^ (r & 15)) << 3),
                    (void*)(raw + (i * 512 + (tid & ~63)) * 8));
    }
    __syncthreads();
    #pragma unroll
    for (int it = 0; it < 4; it++) {
        int idx = it * 512 + tid;
        int s = idx & 127, pg = idx >> 7;
        f16x8 v[4];
        #pragma unroll
        for (int k = 0; k < 4; k++) {
            int rr = s + k;
            uint4 u = *(const uint4*)&raw[rr * 128 + ((pg ^ (rr & 15)) << 3)];
            if (c == 0 && rr < 3) u = make_uint4(0u, 0u, 0u, 0u);
            v[k] = __builtin_bit_cast(f16x8, u);
        }
        #pragma unroll
        for (int j = 0; j < 8; j++) {
            int p = pg * 8 + j;
            float o = scb[0][p] + (float)v[0][j] * scw[0][p][0]
                    + (float)v[1][j] * scw[0][p][1]
                    + (float)v[2][j] * scw[0][p][2]
                    + (float)v[3][j] * scw[0][p][3];
            XT[p * 128 + (((s >> 3) ^ (p & 15)) << 3) + (s & 7)] = f2h(silu_f(o));
        }
    }
    __syncthreads();
    // ---- conv B -> Btok (token-major)
    #pragma unroll
    for (int i = 0; i < 5; i++) {
        int ck = i * 512 + tid;
        int r = ck >> 4; if (r > 130) r = 130;
        int cc = ck & 15;
        int tok = tok0 - 3 + r; if (tok < 0) tok = 0;
        async_lds16(zx16 + (size_t)tok * 768 + 512 + ((cc ^ (r & 15)) << 3),
                    (void*)(raw + (i * 512 + (tid & ~63)) * 8));
    }
    __syncthreads();
    #pragma unroll
    for (int it = 0; it < 4; it++) {
        int idx = it * 512 + tid;
        int t = idx & 127, ng = idx >> 7;
        f16x8 v[4];
        #pragma unroll
        for (int k = 0; k < 4; k++) {
            int rr = t + k;
            uint4 u = *(const uint4*)&raw[rr * 128 + ((ng ^ (rr & 15)) << 3)];
            if (c == 0 && rr < 3) u = make_uint4(0u, 0u, 0u, 0u);
            v[k] = __builtin_bit_cast(f16x8, u);
        }
        union { u16 u[8]; uint4 q; } pk;
        #pragma unroll
        for (int j = 0; j < 8; j++) {
            int n = ng * 8 + j;
            float o = scb[1][n] + (float)v[0][j] * scw[1][n][0]
                    + (float)v[1][j] * scw[1][n][1]
                    + (float)v[2][j] * scw[1][n][2]
                    + (float)v[3][j] * scw[1][n][3];
            pk.u[j] = f2h(silu_f(o));
        }
        *(uint4*)&Btok[t * 128 + ((ng ^ (t & 15)) << 3)] = pk.q;
    }
    __syncthreads();
    // ---- conv C -> Ctok (token-major)
    #pragma unroll
    for (int i = 0; i < 5; i++) {
        int ck = i * 512 + tid;
        int r = ck >> 4; if (r > 130) r = 130;
        int cc = ck & 15;
        int tok = tok0 - 3 + r; if (tok < 0) tok = 0;
        async_lds16(zx16 + (size_t)tok * 768 + 640 + ((cc ^ (r & 15)) << 3),
                    (void*)(raw + (i * 512 + (tid & ~63)) * 8));
    }
    __syncthreads();
    #pragma unroll
    for (int it = 0; it < 4; it++) {
        int idx = it * 512 + tid;
        int t = idx & 127, ng = idx >> 7;
        f16x8 v[4];
        #pragma unroll
        for (int k = 0; k < 4; k++) {
            int rr = t + k;
            uint4 u = *(const uint4*)&raw[rr * 128 + ((ng ^ (rr & 15)) << 3)];
            if (c == 0 && rr < 3) u = make_uint4(0u, 0u, 0u, 0u);
            v[k] = __builtin_bit_cast(f16x8, u);
        }
        union { u16 u[8]; uint4 q; } pk;
        #pragma unroll
        for (int j = 0; j < 8; j++) {
            int n = ng * 8 + j;
            float o = scb[2][n] + (float)v[0][j] * scw[2][n][0]
                    + (float)v[1][j] * scw[2][n][1]
                    + (float)v[2][j] * scw[2][n][2]
                    + (float)v[3][j] * scw[2][n][3];
            pk.u[j] = f2h(silu_f(o));
        }
        *(uint4*)&Ctok[t * 128 + ((ng ^ (t & 15)) << 3)] = pk.q;
    }
    __syncthreads();   // Ctok visible; raw reads done (raw free for G later)
    // ---- phase 1: Y = C @ Hin^T ; Hin fragments direct from global
    const int wm = (wid >> 1) * 32, wn = (wid & 1) * 64;
    f32x4 acc[2][4];
    #pragma unroll
    for (int i = 0; i < 2; i++)
        #pragma unroll
        for (int j = 0; j < 4; j++) acc[i][j] = f32x4{0.f, 0.f, 0.f, 0.f};
    {
        const u16* hg = Hbf + blk;
        #pragma unroll
        for (int ks = 0; ks < 4; ks++) {
            f16x8 ca[2], hb[4];
            int kc = ks * 4 + quad;
            #pragma unroll
            for (int i = 0; i < 2; i++) {
                int r = wm + i * 16 + cl;
                ca[i] = *(const f16x8*)&Ctok[r * 128 + ((kc ^ (r & 15)) << 3)];
            }
            #pragma unroll
            for (int j = 0; j < 4; j++) {
                int r = wn + j * 16 + cl;
                hb[j] = *(const f16x8*)(hg + (size_t)r * 128 + kc * 8);
            }
            #pragma unroll
            for (int i = 0; i < 2; i++)
                #pragma unroll
                for (int j = 0; j < 4; j++)
                    acc[i][j] = __builtin_amdgcn_mfma_f32_16x16x32_f16(
                        ca[i], hb[j], acc[i][j], 0, 0, 0);
        }
    }
    #pragma unroll
    for (int i = 0; i < 2; i++)
        #pragma unroll
        for (int r = 0; r < 4; r++) {
            float e = __expf(sS[wm + i * 16 + quad * 4 + r]);
            #pragma unroll
            for (int j = 0; j < 4; j++) acc[i][j][r] *= e;
        }
    // ---- phase 2: S = C @ B^T (triangular skip)
    f32x4 sacc[2][4];
    #pragma unroll
    for (int i = 0; i < 2; i++)
        #pragma unroll
        for (int j = 0; j < 4; j++) sacc[i][j] = f32x4{0.f, 0.f, 0.f, 0.f};
    #pragma unroll
    for (int ks = 0; ks < 4; ks++) {
        f16x8 cs[2], bs[4];
        int kc = ks * 4 + quad;
        #pragma unroll
        for (int i2 = 0; i2 < 2; i2++) {
            int r = wm + i2 * 16 + cl;
            cs[i2] = *(const f16x8*)&Ctok[r * 128 + ((kc ^ (r & 15)) << 3)];
        }
        #pragma unroll
        for (int j = 0; j < 4; j++) {
            int r = wn + j * 16 + cl;
            bs[j] = *(const f16x8*)&Btok[r * 128 + ((kc ^ (r & 15)) << 3)];
        }
        #pragma unroll
        for (int i2 = 0; i2 < 2; i2++)
            #pragma unroll
            for (int j = 0; j < 4; j++)
                if (wm + i2 * 16 + 15 >= wn + j * 16)
                    sacc[i2][j] = __builtin_amdgcn_mfma_f32_16x16x32_f16(
                        cs[i2], bs[j], sacc[i2][j], 0, 0, 0);
    }
    // ---- G = mask ∘ S ∘ exp(St-Ss) ∘ dt_s  -> raw (raw free since last sync)
    #pragma unroll
    for (int i2 = 0; i2 < 2; i2++)
        #pragma unroll
        for (int r = 0; r < 4; r++) {
            int t = wm + i2 * 16 + quad * 4 + r;
            float Stv = sS[t];
            #pragma unroll
            for (int j = 0; j < 4; j++) {
                int s = wn + j * 16 + cl;
                float gv = 0.f;
                if (s <= t) gv = sacc[i2][j][r] * __expf(Stv - sS[s]) * sdt[s];
                raw[t * 128 + (((s >> 3) ^ (t & 15)) << 3) + (s & 7)] = f2h(gv);
            }
        }
    __syncthreads();
    // ---- phase 3: Y += G @ X
    #pragma unroll
    for (int ks = 0; ks < 4; ks++) {
        f16x8 ga[2], xb[4];
        int kc = ks * 4 + quad;
        #pragma unroll
        for (int i = 0; i < 2; i++) {
            int r = wm + i * 16 + cl;
            ga[i] = *(const f16x8*)&raw[r * 128 + ((kc ^ (r & 15)) << 3)];
        }
        #pragma unroll
        for (int j = 0; j < 4; j++) {
            int r = wn + j * 16 + cl;
            xb[j] = *(const f16x8*)&XT[r * 128 + ((kc ^ (r & 15)) << 3)];
        }
        #pragma unroll
        for (int i = 0; i < 2; i++)
            #pragma unroll
            for (int j = 0; j < 4; j++)
                acc[i][j] = __builtin_amdgcn_mfma_f32_16x16x32_f16(
                    ga[i], xb[j], acc[i][j], 0, 0, 0);
    }
    // ---- epilogue: g = (Y + D*x)*silu(z)
    const float dco = Dp[h];
    #pragma unroll
    for (int i = 0; i < 2; i++)
        #pragma unroll
        for (int r = 0; r < 4; r++) {
            int t = wm + i * 16 + quad * 4 + r;
            u16* row = g16 + (size_t)(tok0 + t) * 256 + h * 128;
            #pragma unroll
            for (int j = 0; j < 4; j++) {
                int p = wn + j * 16 + cl;
                float xv = h2f(XT[p * 128 + (((t >> 3) ^ (p & 15)) << 3) + (t & 7)]);
                float zv = h2f(zx16[(size_t)(tok0 + t) * 768 + h * 128 + p]);
                row[p] = f2h((acc[i][j][r] + dco * xv) * silu_f(zv));
            }
        }
}

// ---------------------------------------------------------------------------
// out-proj GEMM (K=256, N=128, BM=64) + residual + RMS (+ fused final
// projection in mode 3). (unchanged)
// ---------------------------------------------------------------------------
__global__ __launch_bounds__(256) void gemm_outrms_kernel(
    const u16* __restrict__ A, const float* __restrict__ Wf,
    const float* __restrict__ gnw, const float* __restrict__ rmsw,
    u16* __restrict__ xp16, u16* __restrict__ hbuf16, u16* __restrict__ hn16,
    const float* __restrict__ out_wf, const float* __restrict__ out_b,
    float* __restrict__ dout, int mode)
{
    __shared__ u16 sA[64 * 64];
    __shared__ u16 sW[128 * 64];
    __shared__ float red[64][33];
    __shared__ float srstd[64];
    __shared__ float redp[64][5];
    __shared__ float rstdg[64];
    __shared__ u16 hn2[64 * 128];
    __shared__ u16 ow[64 * 128];
    const int K = 256;
    const int m0 = blockIdx.y * 64;
    const int tid = threadIdx.x, wid = tid >> 6, lane = tid & 63;
    const int wm = (wid >> 1) * 32, wn = (wid & 1) * 64;
    const int quad = lane >> 4, cl = lane & 15;
    f32x4 acc[2][4];
    #pragma unroll
    for (int i = 0; i < 2; i++)
        #pragma unroll
        for (int j = 0; j < 4; j++) acc[i][j] = f32x4{0.f, 0.f, 0.f, 0.f};

    float ssq = 0.f;   // per-thread partial sum-of-squares of g (row tid>>2)
    for (int k0 = 0; k0 < K; k0 += 64) {
        #pragma unroll
        for (int i = 0; i < 2; i++) {
            int ck = i * 256 + tid;
            int r = ck >> 3, cc = ck & 7;
            int csw = (cc ^ (r & 7)) << 3;
            async_lds16(A + (size_t)(m0 + r) * K + k0 + csw,
                        (void*)(sA + (i * 256 + (tid & ~63)) * 8));
        }
        #pragma unroll
        for (int i = 0; i < 4; i++) {
            int ck = i * 256 + tid;
            int r = ck >> 3, cc = ck & 7;
            int csw = (cc ^ (r & 7)) << 3;
            *(uint4*)&sW[ck * 8] = cvt8g(Wf + (size_t)r * K + k0 + csw,
                                         gnw + k0 + csw);
        }
        __syncthreads();
        {   // accumulate squares from staged A (swizzle permutes within row)
            int rr = tid >> 2, q = tid & 3;
            f16x8 v0 = *(const f16x8*)&sA[rr * 64 + q * 16];
            f16x8 v1 = *(const f16x8*)&sA[rr * 64 + q * 16 + 8];
            #pragma unroll
            for (int j = 0; j < 8; j++) {
                float a = (float)v0[j], bq = (float)v1[j];
                ssq += a * a + bq * bq;
            }
        }
        #pragma unroll
        for (int ks = 0; ks < 2; ks++) {
            f16x8 af[2], wv[4];
            int kc = ks * 4 + quad;
            #pragma unroll
            for (int i = 0; i < 2; i++) {
                int r = wm + i * 16 + cl;
                af[i] = *(const f16x8*)&sA[r * 64 + ((kc ^ (r & 7)) << 3)];
            }
            #pragma unroll
            for (int j = 0; j < 4; j++) {
                int r = wn + j * 16 + cl;
                wv[j] = *(const f16x8*)&sW[r * 64 + ((kc ^ (r & 7)) << 3)];
            }
            #pragma unroll
            for (int i = 0; i < 2; i++)
                #pragma unroll
                for (int j = 0; j < 4; j++)
                    acc[i][j] = __builtin_amdgcn_mfma_f32_16x16x32_f16(
                        af[i], wv[j], acc[i][j], 0, 0, 0);
        }
        __syncthreads();
    }
    redp[tid >> 2][tid & 3] = ssq;
    __syncthreads();
    if (tid < 64)
        rstdg[tid] = rsqrtf((redp[tid][0] + redp[tid][1] + redp[tid][2]
                             + redp[tid][3]) * (1.f / 256.f) + 1e-5f);
    __syncthreads();
    const int slot = (wid & 1) * 16 + cl;
    #pragma unroll
    for (int i = 0; i < 2; i++)
        #pragma unroll
        for (int r = 0; r < 4; r++) {
            int t = wm + i * 16 + quad * 4 + r;
            size_t ob = (size_t)(m0 + t) * 128;
            float rg = rstdg[t];
            float ssp = 0.f;
            #pragma unroll
            for (int j = 0; j < 4; j++) {
                int n = wn + j * 16 + cl;
                float v = acc[i][j][r] * rg + h2f(hbuf16[ob + n]);
                acc[i][j][r] = v;
                ssp += v * v;
            }
            red[t][slot] = ssp;
        }
    __syncthreads();
    if (tid < 64) {
        float s = 0.f;
        #pragma unroll
        for (int sl = 0; sl < 32; sl++) s += red[tid][sl];
        srstd[tid] = rsqrtf(s * (1.f / 128.f) + 1e-5f);
    }
    __syncthreads();
    #pragma unroll
    for (int i = 0; i < 2; i++)
        #pragma unroll
        for (int r = 0; r < 4; r++) {
            int t = wm + i * 16 + quad * 4 + r;
            size_t ob = (size_t)(m0 + t) * 128;
            float rstd = srstd[t];
            #pragma unroll
            for (int j = 0; j < 4; j++) {
                int n = wn + j * 16 + cl;
                float v = acc[i][j][r];
                float val = v * rstd * rmsw[n];
                if (mode == 1) {
                    hbuf16[ob + n] = f2h(v);
                    hn16[ob + n] = f2h(val);
                } else {
                    val += h2f(xp16[ob + n]);
                    hn2[t * 128 + (((n >> 3) ^ (t & 15)) << 3) + (n & 7)] = f2h(val);
                }
            }
        }
    if (mode == 1) return;
    #pragma unroll
    for (int i = 0; i < 4; i++) {
        int ck = i * 256 + tid;
        int rr = ck >> 4, cc = ck & 15;
        int csw = (cc ^ (rr & 15)) << 3;
        *(uint4*)&ow[ck * 8] = cvt8(out_wf + (size_t)rr * 128 + csw);
    }
    __syncthreads();
    const int wm4 = (wid >> 1) * 32, wn4 = (wid & 1) * 32;
    f32x4 acc2[2][2];
    #pragma unroll
    for (int i = 0; i < 2; i++)
        #pragma unroll
        for (int j = 0; j < 2; j++) acc2[i][j] = f32x4{0.f, 0.f, 0.f, 0.f};
    #pragma unroll
    for (int ks = 0; ks < 4; ks++) {
        f16x8 af2[2], wf2[2];
        int kc = ks * 4 + quad;
        #pragma unroll
        for (int i = 0; i < 2; i++) {
            int r = wm4 + i * 16 + cl;
            af2[i] = *(const f16x8*)&hn2[r * 128 + ((kc ^ (r & 15)) << 3)];
        }
        #pragma unroll
        for (int j = 0; j < 2; j++) {
            int rr = wn4 + j * 16 + cl;
            wf2[j] = *(const f16x8*)&ow[rr * 128 + ((kc ^ (rr & 15)) << 3)];
        }
        #pragma unroll
        for (int i = 0; i < 2; i++)
            #pragma unroll
            for (int j = 0; j < 2; j++)
                acc2[i][j] = __builtin_amdgcn_mfma_f32_16x16x32_f16(
                    af2[i], wf2[j], acc2[i][j], 0, 0, 0);
    }
    #pragma unroll
    for (int i = 0; i < 2; i++) {
        int m = m0 + wm4 + i * 16 + quad * 4;
        #pragma unroll
        for (int j = 0; j < 2; j++) {
            int n = wn4 + j * 16 + cl;
            float bv = out_b[n];
            #pragma unroll
            for (int r = 0; r < 4; r++)
                dout[(size_t)(m + r) * 64 + n] = acc2[i][j][r] + bv;
        }
    }
}

// ---------------------------------------------------------------------------
extern "C" void kernel_launch(void* const* d_in, const int* in_sizes, int n_in,
                              void* d_out, int out_size, void* d_ws, size_t ws_size,
                              hipStream_t stream)
{
    (void)in_sizes; (void)n_in; (void)out_size; (void)ws_size;
    const float* x       = (const float*)d_in[0];
    const float* in_w    = (const float*)d_in[1];
    const float* in_b    = (const float*)d_in[2];
    const float* out_w   = (const float*)d_in[3];
    const float* out_b   = (const float*)d_in[4];
    const float* l_rms_w = (const float*)d_in[5];
    const float* l_in_w  = (const float*)d_in[6];
    const float* conv_w  = (const float*)d_in[7];
    const float* conv_b  = (const float*)d_in[8];
    const float* dt_bias = (const float*)d_in[9];
    const float* A_log   = (const float*)d_in[10];
    const float* D_p     = (const float*)d_in[11];
    const float* gnorm_w = (const float*)d_in[12];
    const float* l_out_w = (const float*)d_in[13];
    const float* fnorm_w = (const float*)d_in[14];

    char* w = (char*)d_ws;
    u16*   xp16   = (u16*)(w);                  // 4.19 MB
    u16*   hbuf16 = (u16*)(w + 4194304);        // 4.19 MB
    u16*   hn16   = (u16*)(w + 8388608);        // 4.19 MB
    u16*   zx16   = (u16*)(w + 12582912);       // 25.17 MB
    float* dtb    = (float*)(w + 37748736);     // 131 KB
    float* Sb     = (float*)(w + 37879808);     // 131 KB
    u16*   Hb     = (u16*)(w + 38010880);       // 8.39 MB
    u16*   Hbf    = (u16*)(w + 46399488);       // 8.39 MB
    u16*   g16    = (u16*)(w + 54788096);       // 8.39 MB

    gemm_rms0_kernel<<<dim3(1, 256), 256, 0, stream>>>(
        x, in_w, in_b, l_rms_w, xp16, hbuf16, hn16);

    for (int i = 0; i < 2; i++) {
        gemm_inproj_kernel<<<dim3(7, 128), 256, 0, stream>>>(
            hn16, l_in_w + (size_t)i * 770 * 128, zx16, dtb, Sb,
            dt_bias + i * 2, A_log + i * 2);
        chunkstate_conv_kernel<<<dim3(32, 2, 4), 512, 0, stream>>>(
            zx16, conv_w + i * 2048, conv_b + i * 512, dtb, Sb, Hb);
        statecombine_kernel<<<dim3(32, 2, 4), 256, 0, stream>>>(Sb, Hb, Hbf);
        ssd_ph_kernel<<<dim3(32, 2, 4), 512, 0, stream>>>(
            zx16, Hbf, dtb, Sb, conv_w + i * 2048, conv_b + i * 512,
            D_p + i * 2, g16);
        gemm_outrms_kernel<<<dim3(1, 256), 256, 0, stream>>>(
            g16, l_out_w + (size_t)i * 128 * 256, gnorm_w + i * 256,
            (i == 0) ? (l_rms_w + 128) : fnorm_w, xp16, hbuf16, hn16,
            out_w, out_b, (float*)d_out, (i == 0) ? 1 : 3);
    }
}

// Round 5
// 229.210 us; speedup vs baseline: 1.7531x; 1.2750x over previous
//
#include <hip/hip_runtime.h>
#include <cstddef>
#include <cstdint>

// MambaDoc — round 18: R17 (vectorized epilogues) with the rms0 store-loop
// iteration-count bug fixed (2 -> 4: 64 rows x 16 col-groups = 1024 uint4
// stores needs 4 iters of 256 threads; R17 only wrote rows 0-31).
// Mechanism: ssd/chunkstate/rms0 epilogues transpose through an already-free
// LDS buffer and do coalesced uint4 I/O instead of 32-96 scalar u16 ops.
// Staging/barrier structure = exact R13 (226.07 µs verified).

#define LSEQ 4096
#define MTOK 16384

typedef unsigned short u16;
typedef _Float16 f16x8 __attribute__((ext_vector_type(8)));
typedef float f32x4 __attribute__((ext_vector_type(4)));

__device__ __forceinline__ u16 f2h(float x) {
    return __builtin_bit_cast(u16, (_Float16)x);
}
__device__ __forceinline__ float h2f(u16 u) {
    return (float)__builtin_bit_cast(_Float16, u);
}
__device__ __forceinline__ float silu_f(float x) { return x / (1.f + __expf(-x)); }

__device__ __forceinline__ void async_lds16(const void* g, void* l) {
    __builtin_amdgcn_global_load_lds(
        (const __attribute__((address_space(1))) unsigned int*)g,
        (__attribute__((address_space(3))) unsigned int*)l, 16, 0, 0);
}

__device__ __forceinline__ uint4 cvt8(const float* __restrict__ src) {
    float4 a = *(const float4*)src;
    float4 b = *(const float4*)(src + 4);
    union { u16 u[8]; uint4 q; } pk;
    pk.u[0] = f2h(a.x); pk.u[1] = f2h(a.y); pk.u[2] = f2h(a.z); pk.u[3] = f2h(a.w);
    pk.u[4] = f2h(b.x); pk.u[5] = f2h(b.y); pk.u[6] = f2h(b.z); pk.u[7] = f2h(b.w);
    return pk.q;
}

__device__ __forceinline__ uint4 cvt8g(const float* __restrict__ src,
                                       const float* __restrict__ gw) {
    float4 a = *(const float4*)src;
    float4 b = *(const float4*)(src + 4);
    float4 ga = *(const float4*)gw;
    float4 gb = *(const float4*)(gw + 4);
    union { u16 u[8]; uint4 q; } pk;
    pk.u[0] = f2h(a.x * ga.x); pk.u[1] = f2h(a.y * ga.y);
    pk.u[2] = f2h(a.z * ga.z); pk.u[3] = f2h(a.w * ga.w);
    pk.u[4] = f2h(b.x * gb.x); pk.u[5] = f2h(b.y * gb.y);
    pk.u[6] = f2h(b.z * gb.z); pk.u[7] = f2h(b.w * gb.w);
    return pk.q;
}

// ---------------------------------------------------------------------------
// Initial projection + fused RMSNorm. BM=64, grid (1,256).
// R18: vectorized triple-store epilogue via sW transpose (bit-identical math).
// ---------------------------------------------------------------------------
__global__ __launch_bounds__(256) void gemm_rms0_kernel(
    const float* __restrict__ xf, const float* __restrict__ wf,
    const float* __restrict__ bias, const float* __restrict__ rmsw,
    u16* __restrict__ xp16, u16* __restrict__ hbuf16, u16* __restrict__ hn16)
{
    __shared__ u16 sA[64 * 64];
    __shared__ u16 sW[128 * 64];
    __shared__ float red[64][33];
    __shared__ float srstd[64];
    const int m0 = blockIdx.y * 64;
    const int tid = threadIdx.x, wid = tid >> 6, lane = tid & 63;
    const int wm = (wid >> 1) * 32, wn = (wid & 1) * 64;
    const int quad = lane >> 4, cl = lane & 15;
    #pragma unroll
    for (int i = 0; i < 2; i++) {
        int ck = i * 256 + tid;
        int r = ck >> 3, cc = ck & 7;
        int csw = (cc ^ (r & 7)) << 3;
        *(uint4*)&sA[ck * 8] = cvt8(xf + (size_t)(m0 + r) * 64 + csw);
    }
    #pragma unroll
    for (int i = 0; i < 4; i++) {
        int ck = i * 256 + tid;
        int r = ck >> 3, cc = ck & 7;
        int csw = (cc ^ (r & 7)) << 3;
        *(uint4*)&sW[ck * 8] = cvt8(wf + (size_t)r * 64 + csw);
    }
    __syncthreads();
    f32x4 acc[2][4];
    #pragma unroll
    for (int i = 0; i < 2; i++)
        #pragma unroll
        for (int j = 0; j < 4; j++) acc[i][j] = f32x4{0.f, 0.f, 0.f, 0.f};
    #pragma unroll
    for (int ks = 0; ks < 2; ks++) {
        f16x8 af[2], wv[4];
        int kc = ks * 4 + quad;
        #pragma unroll
        for (int i = 0; i < 2; i++) {
            int r = wm + i * 16 + cl;
            af[i] = *(const f16x8*)&sA[r * 64 + ((kc ^ (r & 7)) << 3)];
        }
        #pragma unroll
        for (int j = 0; j < 4; j++) {
            int r = wn + j * 16 + cl;
            wv[j] = *(const f16x8*)&sW[r * 64 + ((kc ^ (r & 7)) << 3)];
        }
        #pragma unroll
        for (int i = 0; i < 2; i++)
            #pragma unroll
            for (int j = 0; j < 4; j++)
                acc[i][j] = __builtin_amdgcn_mfma_f32_16x16x32_f16(
                    af[i], wv[j], acc[i][j], 0, 0, 0);
    }
    const int slot = (wid & 1) * 16 + cl;
    #pragma unroll
    for (int i = 0; i < 2; i++)
        #pragma unroll
        for (int r = 0; r < 4; r++) {
            int t = wm + i * 16 + quad * 4 + r;
            float ssp = 0.f;
            #pragma unroll
            for (int j = 0; j < 4; j++) {
                int n = wn + j * 16 + cl;
                float v = acc[i][j][r] + bias[n];
                acc[i][j][r] = v;
                ssp += v * v;
            }
            red[t][slot] = ssp;
        }
    __syncthreads();
    if (tid < 64) {
        float s = 0.f;
        #pragma unroll
        for (int sl = 0; sl < 32; sl++) s += red[tid][sl];
        srstd[tid] = rsqrtf(s * (1.f / 128.f) + 1e-5f);
    }
    __syncthreads();
    // pass 1: v tile -> sW (free after MFMA), then vector stores xp16/hbuf16
    #pragma unroll
    for (int i = 0; i < 2; i++)
        #pragma unroll
        for (int r = 0; r < 4; r++) {
            int t = wm + i * 16 + quad * 4 + r;
            #pragma unroll
            for (int j = 0; j < 4; j++) {
                int n = wn + j * 16 + cl;
                sW[t * 128 + (((n >> 3) ^ (t & 15)) << 3) + (n & 7)]
                    = f2h(acc[i][j][r]);
            }
        }
    __syncthreads();
    #pragma unroll
    for (int it = 0; it < 4; it++) {
        int id = it * 256 + tid;
        int rr = id >> 4, c8 = id & 15;
        uint4 v = *(const uint4*)&sW[rr * 128 + ((c8 ^ (rr & 15)) << 3)];
        *(uint4*)&xp16[(size_t)(m0 + rr) * 128 + c8 * 8] = v;
        *(uint4*)&hbuf16[(size_t)(m0 + rr) * 128 + c8 * 8] = v;
    }
    __syncthreads();
    // pass 2: hn tile -> sW, then vector store hn16
    #pragma unroll
    for (int i = 0; i < 2; i++)
        #pragma unroll
        for (int r = 0; r < 4; r++) {
            int t = wm + i * 16 + quad * 4 + r;
            float rstd = srstd[t];
            #pragma unroll
            for (int j = 0; j < 4; j++) {
                int n = wn + j * 16 + cl;
                sW[t * 128 + (((n >> 3) ^ (t & 15)) << 3) + (n & 7)]
                    = f2h(acc[i][j][r] * rstd * rmsw[n]);
            }
        }
    __syncthreads();
    #pragma unroll
    for (int it = 0; it < 4; it++) {
        int id = it * 256 + tid;
        int rr = id >> 4, c8 = id & 15;
        *(uint4*)&hn16[(size_t)(m0 + rr) * 128 + c8 * 8]
            = *(const uint4*)&sW[rr * 128 + ((c8 ^ (rr & 15)) << 3)];
    }
}

// ---------------------------------------------------------------------------
// in_proj GEMM fp16 (K=128). Grid (7, 128). (unchanged R13)
// ---------------------------------------------------------------------------
__global__ __launch_bounds__(256) void gemm_inproj_kernel(
    const u16* __restrict__ A, const float* __restrict__ Wf,
    u16* __restrict__ zx16, float* __restrict__ dtb, float* __restrict__ Sb,
    const float* __restrict__ dt_bias, const float* __restrict__ A_log)
{
    __shared__ u16 sA[128 * 64];
    __shared__ u16 sW[128 * 64];
    __shared__ float sdt[2][128];
    const int K = 128, N = 770;
    const int n0 = blockIdx.x * 128, m0 = blockIdx.y * 128;
    const int tid = threadIdx.x, wid = tid >> 6, lane = tid & 63;
    const int wm = (wid >> 1) * 64, wn = (wid & 1) * 64;
    const int quad = lane >> 4, cl = lane & 15;
    f32x4 acc[4][4];
    #pragma unroll
    for (int i = 0; i < 4; i++)
        #pragma unroll
        for (int j = 0; j < 4; j++) acc[i][j] = f32x4{0.f, 0.f, 0.f, 0.f};

    for (int k0 = 0; k0 < K; k0 += 64) {
        #pragma unroll
        for (int i = 0; i < 4; i++) {
            int ck = i * 256 + tid;
            int r = ck >> 3, cc = ck & 7;
            int csw = (cc ^ (r & 7)) << 3;
            async_lds16(A + (size_t)(m0 + r) * K + k0 + csw,
                        (void*)(sA + (i * 256 + (tid & ~63)) * 8));
        }
        #pragma unroll
        for (int i = 0; i < 4; i++) {
            int ck = i * 256 + tid;
            int r = ck >> 3, cc = ck & 7;
            int csw = (cc ^ (r & 7)) << 3;
            int rr = n0 + r; if (rr >= N) rr = N - 1;
            *(uint4*)&sW[ck * 8] = cvt8(Wf + (size_t)rr * K + k0 + csw);
        }
        __syncthreads();
        #pragma unroll
        for (int ks = 0; ks < 2; ks++) {
            f16x8 af[4], wv[4];
            int kc = ks * 4 + quad;
            #pragma unroll
            for (int i = 0; i < 4; i++) {
                int r = wm + i * 16 + cl;
                af[i] = *(const f16x8*)&sA[r * 64 + ((kc ^ (r & 7)) << 3)];
            }
            #pragma unroll
            for (int j = 0; j < 4; j++) {
                int r = wn + j * 16 + cl;
                wv[j] = *(const f16x8*)&sW[r * 64 + ((kc ^ (r & 7)) << 3)];
            }
            #pragma unroll
            for (int i = 0; i < 4; i++)
                #pragma unroll
                for (int j = 0; j < 4; j++)
                    acc[i][j] = __builtin_amdgcn_mfma_f32_16x16x32_f16(
                        af[i], wv[j], acc[i][j], 0, 0, 0);
        }
        __syncthreads();
    }
    if (blockIdx.x < 6) {
        #pragma unroll
        for (int i = 0; i < 4; i++) {
            int m = m0 + wm + i * 16 + quad * 4;
            #pragma unroll
            for (int j = 0; j < 4; j++) {
                int n = n0 + wn + j * 16 + cl;
                #pragma unroll
                for (int r = 0; r < 4; r++)
                    zx16[(size_t)(m + r) * 768 + n] = f2h(acc[i][j][r]);
            }
        }
    } else {
        if ((wid & 1) == 0 && cl < 2) {
            #pragma unroll
            for (int i = 0; i < 4; i++)
                #pragma unroll
                for (int r = 0; r < 4; r++)
                    sdt[cl][wm + i * 16 + quad * 4 + r] = acc[i][0][r];
        }
        __syncthreads();
        const int hh = tid >> 7, t = tid & 127;
        float raw = sdt[hh][t] + dt_bias[hh];
        float dt = fmaxf(raw, 0.f) + log1pf(__expf(-fabsf(raw)));
        dtb[(size_t)(m0 + t) * 2 + hh] = dt;
        float ad = -__expf(A_log[hh]) * dt;
        __syncthreads();
        sdt[hh][t] = ad;
        __syncthreads();
        for (int off = 1; off < 128; off <<= 1) {
            float add = (t >= off) ? sdt[hh][t - off] : 0.f;
            __syncthreads();
            sdt[hh][t] += add;
            __syncthreads();
        }
        Sb[(size_t)(m0 + t) * 2 + hh] = sdt[hh][t];
    }
}

// ---------------------------------------------------------------------------
// chunkstate + inlined conv. Grid (32,2,4), 512 thr. (R13 structure)
// R18: Hb writeback via raw transpose -> coalesced dwordx4 (bit-identical).
// ---------------------------------------------------------------------------
__global__ __launch_bounds__(512) void chunkstate_conv_kernel(
    const u16* __restrict__ zx16, const float* __restrict__ cw,
    const float* __restrict__ cb, const float* __restrict__ dtb,
    const float* __restrict__ Sb, u16* __restrict__ Hb)
{
    __shared__ u16 raw[2560 * 8];
    __shared__ u16 XT[128 * 128];
    __shared__ u16 BT[128 * 128];
    __shared__ float scw[2][128][4];
    __shared__ float scb[2][128];
    __shared__ float ssw[128];
    const int c = blockIdx.x, h = blockIdx.y, b = blockIdx.z;
    const int tid = threadIdx.x, wid = tid >> 6, lane = tid & 63;
    const int quad = lane >> 4, cl = lane & 15;
    const int tok0 = b * LSEQ + c * 128;
    for (int idx = tid; idx < 256; idx += 512) {
        int grp = idx >> 7, j = idx & 127;
        int ch = grp ? (256 + j) : (128 * h + j);
        float4 w4 = *(const float4*)&cw[ch * 4];
        scw[grp][j][0] = w4.x; scw[grp][j][1] = w4.y;
        scw[grp][j][2] = w4.z; scw[grp][j][3] = w4.w;
        scb[grp][j] = cb[ch];
    }
    if (tid < 128) {
        float Sl = Sb[(size_t)(tok0 + 127) * 2 + h];
        ssw[tid] = __expf(Sl - Sb[(size_t)(tok0 + tid) * 2 + h])
                   * dtb[(size_t)(tok0 + tid) * 2 + h];
    }
    #pragma unroll
    for (int i = 0; i < 5; i++) {
        int ck = i * 512 + tid;
        int r = ck >> 4; if (r > 130) r = 130;
        int cc = ck & 15;
        int tok = tok0 - 3 + r; if (tok < 0) tok = 0;
        async_lds16(zx16 + (size_t)tok * 768 + 256 + 128 * h + ((cc ^ (r & 15)) << 3),
                    (void*)(raw + (i * 512 + (tid & ~63)) * 8));
    }
    __syncthreads();
    if (c == 0 && tid < 48) *(uint4*)&raw[tid * 8] = make_uint4(0, 0, 0, 0);
    __syncthreads();
    #pragma unroll
    for (int it = 0; it < 4; it++) {
        int idx = it * 512 + tid;
        int s = idx & 127, pg = idx >> 7;
        f16x8 v[4];
        #pragma unroll
        for (int k = 0; k < 4; k++) {
            int rr = s + k;
            v[k] = *(const f16x8*)&raw[rr * 128 + ((pg ^ (rr & 15)) << 3)];
        }
        #pragma unroll
        for (int j = 0; j < 8; j++) {
            int p = pg * 8 + j;
            float o = scb[0][p] + (float)v[0][j] * scw[0][p][0]
                    + (float)v[1][j] * scw[0][p][1]
                    + (float)v[2][j] * scw[0][p][2]
                    + (float)v[3][j] * scw[0][p][3];
            o = silu_f(o);
            XT[p * 128 + (((s >> 3) ^ (p & 15)) << 3) + (s & 7)] = f2h(o);
        }
    }
    __syncthreads();
    #pragma unroll
    for (int i = 0; i < 5; i++) {
        int ck = i * 512 + tid;
        int r = ck >> 4; if (r > 130) r = 130;
        int cc = ck & 15;
        int tok = tok0 - 3 + r; if (tok < 0) tok = 0;
        async_lds16(zx16 + (size_t)tok * 768 + 512 + ((cc ^ (r & 15)) << 3),
                    (void*)(raw + (i * 512 + (tid & ~63)) * 8));
    }
    __syncthreads();
    if (c == 0 && tid < 48) *(uint4*)&raw[tid * 8] = make_uint4(0, 0, 0, 0);
    __syncthreads();
    #pragma unroll
    for (int it = 0; it < 4; it++) {
        int idx = it * 512 + tid;
        int s = idx & 127, ng = idx >> 7;
        f16x8 v[4];
        #pragma unroll
        for (int k = 0; k < 4; k++) {
            int rr = s + k;
            v[k] = *(const f16x8*)&raw[rr * 128 + ((ng ^ (rr & 15)) << 3)];
        }
        float wsv = ssw[s];
        #pragma unroll
        for (int j = 0; j < 8; j++) {
            int n = ng * 8 + j;
            float o = scb[1][n] + (float)v[0][j] * scw[1][n][0]
                    + (float)v[1][j] * scw[1][n][1]
                    + (float)v[2][j] * scw[1][n][2]
                    + (float)v[3][j] * scw[1][n][3];
            o = silu_f(o) * wsv;
            BT[n * 128 + (((s >> 3) ^ (n & 15)) << 3) + (s & 7)] = f2h(o);
        }
    }
    __syncthreads();
    const size_t blk = ((size_t)((b * 2 + h) * 32 + c)) << 14;
    const int wm = (wid >> 1) * 32, wn = (wid & 1) * 64;
    f32x4 acc[2][4];
    #pragma unroll
    for (int i = 0; i < 2; i++)
        #pragma unroll
        for (int j = 0; j < 4; j++) acc[i][j] = f32x4{0.f, 0.f, 0.f, 0.f};
    #pragma unroll
    for (int ks = 0; ks < 4; ks++) {
        f16x8 xa[2], bb[4];
        int kc = ks * 4 + quad;
        #pragma unroll
        for (int i = 0; i < 2; i++) {
            int r = wm + i * 16 + cl;
            xa[i] = *(const f16x8*)&XT[r * 128 + ((kc ^ (r & 15)) << 3)];
        }
        #pragma unroll
        for (int j = 0; j < 4; j++) {
            int r = wn + j * 16 + cl;
            bb[j] = *(const f16x8*)&BT[r * 128 + ((kc ^ (r & 15)) << 3)];
        }
        #pragma unroll
        for (int i = 0; i < 2; i++)
            #pragma unroll
            for (int j = 0; j < 4; j++)
                acc[i][j] = __builtin_amdgcn_mfma_f32_16x16x32_f16(
                    xa[i], bb[j], acc[i][j], 0, 0, 0);
    }
    // transpose acc through raw (free since conv-B), then coalesced stores
    #pragma unroll
    for (int i = 0; i < 2; i++)
        #pragma unroll
        for (int j = 0; j < 4; j++)
            #pragma unroll
            for (int r = 0; r < 4; r++) {
                int p = wm + i * 16 + quad * 4 + r;
                int n = wn + j * 16 + cl;
                raw[p * 128 + (((n >> 3) ^ (p & 15)) << 3) + (n & 7)]
                    = f2h(acc[i][j][r]);
            }
    __syncthreads();
    u16* out = Hb + blk;
    #pragma unroll
    for (int it = 0; it < 4; it++) {
        int id = it * 512 + tid;
        int rr = id >> 4, c8 = id & 15;
        *(uint4*)&out[(size_t)rr * 128 + c8 * 8]
            = *(const uint4*)&raw[rr * 128 + ((c8 ^ (rr & 15)) << 3)];
    }
}

// ---------------------------------------------------------------------------
// Inter-chunk combine — register-prefetch. Grid (32,2,4), 256 thr. (unchanged)
// ---------------------------------------------------------------------------
__global__ __launch_bounds__(256) void statecombine_kernel(
    const float* __restrict__ Sb, const u16* __restrict__ Hb,
    u16* __restrict__ Hbf)
{
    __shared__ float sdec[32];
    const int h = blockIdx.y, b = blockIdx.z;
    const int e2 = blockIdx.x * 256 + threadIdx.x;
    if (threadIdx.x < 32)
        sdec[threadIdx.x] =
            __expf(Sb[(size_t)(b * LSEQ + threadIdx.x * 128 + 127) * 2 + h]);
    const size_t base2 = ((size_t)((b * 2 + h) * 32)) << 13;
    const unsigned int* src = (const unsigned int*)Hb;
    unsigned int* dst = (unsigned int*)Hbf;
    unsigned int v[32];
    #pragma unroll
    for (int c = 0; c < 32; c++)
        v[c] = src[base2 + ((size_t)c << 13) + e2];
    __syncthreads();
    float s0 = 0.f, s1 = 0.f;
    #pragma unroll
    for (int c = 0; c < 32; c++) {
        union { u16 u[2]; unsigned int q; } pk;
        pk.u[0] = f2h(s0); pk.u[1] = f2h(s1);
        dst[base2 + ((size_t)c << 13) + e2] = pk.q;
        float d = sdec[c];
        s0 = d * s0 + h2f((u16)(v[c] & 0xffffu));
        s1 = d * s1 + h2f((u16)(v[c] >> 16));
    }
}

// ---------------------------------------------------------------------------
// Per-head fused SSD (R13 structure: Hin staged via LDS).
// Grid (32,2,4), 512 thr, ~145 KB LDS.
// R18: vectorized epilogue via raw transpose (uint4 z-loads / g16-stores).
// ---------------------------------------------------------------------------
__global__ __launch_bounds__(512) void ssd_ph_kernel(
    const u16* __restrict__ zx16, const u16* __restrict__ Hbf,
    const float* __restrict__ dtb, const float* __restrict__ Sb,
    const float* __restrict__ cw, const float* __restrict__ cb,
    const float* __restrict__ Dp, u16* __restrict__ g16)
{
    __shared__ u16 raw[2560 * 8];     // staging -> Hin -> G -> Y
    __shared__ u16 XT[128 * 128];
    __shared__ u16 Btok[128 * 128];
    __shared__ u16 Ctok[128 * 128];
    __shared__ float sS[128], sdt[128];
    __shared__ float scw[3][128][4];
    __shared__ float scb[3][128];
    const int c = blockIdx.x, h = blockIdx.y, b = blockIdx.z;
    const int tid = threadIdx.x, wid = tid >> 6, lane = tid & 63;
    const int quad = lane >> 4, cl = lane & 15;
    const int tok0 = b * LSEQ + c * 128;
    const size_t blk = ((size_t)((b * 2 + h) * 32 + c)) << 14;
    for (int idx = tid; idx < 384; idx += 512) {
        int grp = idx >> 7, j = idx & 127;
        int ch = (grp == 0) ? (128 * h + j) : (grp == 1 ? 256 + j : 384 + j);
        float4 w4 = *(const float4*)&cw[ch * 4];
        scw[grp][j][0] = w4.x; scw[grp][j][1] = w4.y;
        scw[grp][j][2] = w4.z; scw[grp][j][3] = w4.w;
        scb[grp][j] = cb[ch];
    }
    if (tid < 128) {
        sS[tid] = Sb[(size_t)(tok0 + tid) * 2 + h];
        sdt[tid] = dtb[(size_t)(tok0 + tid) * 2 + h];
    }
    // ---- conv X -> XT
    #pragma unroll
    for (int i = 0; i < 5; i++) {
        int ck = i * 512 + tid;
        int r = ck >> 4; if (r > 130) r = 130;
        int cc = ck & 15;
        int tok = tok0 - 3 + r; if (tok < 0) tok = 0;
        async_lds16(zx16 + (size_t)tok * 768 + 256 + 128 * h + ((cc ^ (r & 15)) << 3),
                    (void*)(raw + (i * 512 + (tid & ~63)) * 8));
    }
    __syncthreads();
    if (c == 0 && tid < 48) *(uint4*)&raw[tid * 8] = make_uint4(0, 0, 0, 0);
    __syncthreads();
    #pragma unroll
    for (int it = 0; it < 4; it++) {
        int idx = it * 512 + tid;
        int s = idx & 127, pg = idx >> 7;
        f16x8 v[4];
        #pragma unroll
        for (int k = 0; k < 4; k++) {
            int rr = s + k;
            v[k] = *(const f16x8*)&raw[rr * 128 + ((pg ^ (rr & 15)) << 3)];
        }
        #pragma unroll
        for (int j = 0; j < 8; j++) {
            int p = pg * 8 + j;
            float o = scb[0][p] + (float)v[0][j] * scw[0][p][0]
                    + (float)v[1][j] * scw[0][p][1]
                    + (float)v[2][j] * scw[0][p][2]
                    + (float)v[3][j] * scw[0][p][3];
            XT[p * 128 + (((s >> 3) ^ (p & 15)) << 3) + (s & 7)] = f2h(silu_f(o));
        }
    }
    __syncthreads();
    // ---- conv B -> Btok (token-major)
    #pragma unroll
    for (int i = 0; i < 5; i++) {
        int ck = i * 512 + tid;
        int r = ck >> 4; if (r > 130) r = 130;
        int cc = ck & 15;
        int tok = tok0 - 3 + r; if (tok < 0) tok = 0;
        async_lds16(zx16 + (size_t)tok * 768 + 512 + ((cc ^ (r & 15)) << 3),
                    (void*)(raw + (i * 512 + (tid & ~63)) * 8));
    }
    __syncthreads();
    if (c == 0 && tid < 48) *(uint4*)&raw[tid * 8] = make_uint4(0, 0, 0, 0);
    __syncthreads();
    #pragma unroll
    for (int it = 0; it < 4; it++) {
        int idx = it * 512 + tid;
        int t = idx & 127, ng = idx >> 7;
        f16x8 v[4];
        #pragma unroll
        for (int k = 0; k < 4; k++) {
            int rr = t + k;
            v[k] = *(const f16x8*)&raw[rr * 128 + ((ng ^ (rr & 15)) << 3)];
        }
        union { u16 u[8]; uint4 q; } pk;
        #pragma unroll
        for (int j = 0; j < 8; j++) {
            int n = ng * 8 + j;
            float o = scb[1][n] + (float)v[0][j] * scw[1][n][0]
                    + (float)v[1][j] * scw[1][n][1]
                    + (float)v[2][j] * scw[1][n][2]
                    + (float)v[3][j] * scw[1][n][3];
            pk.u[j] = f2h(silu_f(o));
        }
        *(uint4*)&Btok[t * 128 + ((ng ^ (t & 15)) << 3)] = pk.q;
    }
    __syncthreads();
    // ---- conv C -> Ctok (token-major)
    #pragma unroll
    for (int i = 0; i < 5; i++) {
        int ck = i * 512 + tid;
        int r = ck >> 4; if (r > 130) r = 130;
        int cc = ck & 15;
        int tok = tok0 - 3 + r; if (tok < 0) tok = 0;
        async_lds16(zx16 + (size_t)tok * 768 + 640 + ((cc ^ (r & 15)) << 3),
                    (void*)(raw + (i * 512 + (tid & ~63)) * 8));
    }
    __syncthreads();
    if (c == 0 && tid < 48) *(uint4*)&raw[tid * 8] = make_uint4(0, 0, 0, 0);
    __syncthreads();
    #pragma unroll
    for (int it = 0; it < 4; it++) {
        int idx = it * 512 + tid;
        int t = idx & 127, ng = idx >> 7;
        f16x8 v[4];
        #pragma unroll
        for (int k = 0; k < 4; k++) {
            int rr = t + k;
            v[k] = *(const f16x8*)&raw[rr * 128 + ((ng ^ (rr & 15)) << 3)];
        }
        union { u16 u[8]; uint4 q; } pk;
        #pragma unroll
        for (int j = 0; j < 8; j++) {
            int n = ng * 8 + j;
            float o = scb[2][n] + (float)v[0][j] * scw[2][n][0]
                    + (float)v[1][j] * scw[2][n][1]
                    + (float)v[2][j] * scw[2][n][2]
                    + (float)v[3][j] * scw[2][n][3];
            pk.u[j] = f2h(silu_f(o));
        }
        *(uint4*)&Ctok[t * 128 + ((ng ^ (t & 15)) << 3)] = pk.q;
    }
    __syncthreads();   // raw free -> stage Hin
    #pragma unroll
    for (int i = 0; i < 4; i++) {
        int ck = i * 512 + tid;
        int r = ck >> 4, cc = ck & 15;
        async_lds16(Hbf + blk + (size_t)r * 128 + ((cc ^ (r & 15)) << 3),
                    (void*)(raw + (i * 512 + (tid & ~63)) * 8));
    }
    __syncthreads();
    // ---- phase 1: Y = C @ Hin^T ; scale by exp(S_t)
    const int wm = (wid >> 1) * 32, wn = (wid & 1) * 64;
    f32x4 acc[2][4];
    #pragma unroll
    for (int i = 0; i < 2; i++)
        #pragma unroll
        for (int j = 0; j < 4; j++) acc[i][j] = f32x4{0.f, 0.f, 0.f, 0.f};
    #pragma unroll
    for (int ks = 0; ks < 4; ks++) {
        f16x8 ca[2], hb[4];
        int kc = ks * 4 + quad;
        #pragma unroll
        for (int i = 0; i < 2; i++) {
            int r = wm + i * 16 + cl;
            ca[i] = *(const f16x8*)&Ctok[r * 128 + ((kc ^ (r & 15)) << 3)];
        }
        #pragma unroll
        for (int j = 0; j < 4; j++) {
            int r = wn + j * 16 + cl;
            hb[j] = *(const f16x8*)&raw[r * 128 + ((kc ^ (r & 15)) << 3)];
        }
        #pragma unroll
        for (int i = 0; i < 2; i++)
            #pragma unroll
            for (int j = 0; j < 4; j++)
                acc[i][j] = __builtin_amdgcn_mfma_f32_16x16x32_f16(
                    ca[i], hb[j], acc[i][j], 0, 0, 0);
    }
    #pragma unroll
    for (int i = 0; i < 2; i++)
        #pragma unroll
        for (int r = 0; r < 4; r++) {
            float e = __expf(sS[wm + i * 16 + quad * 4 + r]);
            #pragma unroll
            for (int j = 0; j < 4; j++) acc[i][j][r] *= e;
        }
    // ---- phase 2: S = C @ B^T (triangular skip)
    f32x4 sacc[2][4];
    #pragma unroll
    for (int i = 0; i < 2; i++)
        #pragma unroll
        for (int j = 0; j < 4; j++) sacc[i][j] = f32x4{0.f, 0.f, 0.f, 0.f};
    #pragma unroll
    for (int ks = 0; ks < 4; ks++) {
        f16x8 cs[2], bs[4];
        int kc = ks * 4 + quad;
        #pragma unroll
        for (int i2 = 0; i2 < 2; i2++) {
            int r = wm + i2 * 16 + cl;
            cs[i2] = *(const f16x8*)&Ctok[r * 128 + ((kc ^ (r & 15)) << 3)];
        }
        #pragma unroll
        for (int j = 0; j < 4; j++) {
            int r = wn + j * 16 + cl;
            bs[j] = *(const f16x8*)&Btok[r * 128 + ((kc ^ (r & 15)) << 3)];
        }
        #pragma unroll
        for (int i2 = 0; i2 < 2; i2++)
            #pragma unroll
            for (int j = 0; j < 4; j++)
                if (wm + i2 * 16 + 15 >= wn + j * 16)
                    sacc[i2][j] = __builtin_amdgcn_mfma_f32_16x16x32_f16(
                        cs[i2], bs[j], sacc[i2][j], 0, 0, 0);
    }
    __syncthreads();   // all reads of raw(Hin) done
    // ---- G = mask ∘ S ∘ exp(St-Ss) ∘ dt_s  -> raw (over Hin)
    #pragma unroll
    for (int i2 = 0; i2 < 2; i2++)
        #pragma unroll
        for (int r = 0; r < 4; r++) {
            int t = wm + i2 * 16 + quad * 4 + r;
            float Stv = sS[t];
            #pragma unroll
            for (int j = 0; j < 4; j++) {
                int s = wn + j * 16 + cl;
                float gv = 0.f;
                if (s <= t) gv = sacc[i2][j][r] * __expf(Stv - sS[s]) * sdt[s];
                raw[t * 128 + (((s >> 3) ^ (t & 15)) << 3) + (s & 7)] = f2h(gv);
            }
        }
    __syncthreads();
    // ---- phase 3: Y += G @ X
    #pragma unroll
    for (int ks = 0; ks < 4; ks++) {
        f16x8 ga[2], xb[4];
        int kc = ks * 4 + quad;
        #pragma unroll
        for (int i = 0; i < 2; i++) {
            int r = wm + i * 16 + cl;
            ga[i] = *(const f16x8*)&raw[r * 128 + ((kc ^ (r & 15)) << 3)];
        }
        #pragma unroll
        for (int j = 0; j < 4; j++) {
            int r = wn + j * 16 + cl;
            xb[j] = *(const f16x8*)&XT[r * 128 + ((kc ^ (r & 15)) << 3)];
        }
        #pragma unroll
        for (int i = 0; i < 2; i++)
            #pragma unroll
            for (int j = 0; j < 4; j++)
                acc[i][j] = __builtin_amdgcn_mfma_f32_16x16x32_f16(
                    ga[i], xb[j], acc[i][j], 0, 0, 0);
    }
    __syncthreads();   // all waves done reading G(raw) before Y overwrites it
    // ---- epilogue: Y + D*x -> raw [t][p], then vectorized gate + store
    const float dco = Dp[h];
    #pragma unroll
    for (int i = 0; i < 2; i++)
        #pragma unroll
        for (int r = 0; r < 4; r++) {
            int t = wm + i * 16 + quad * 4 + r;
            #pragma unroll
            for (int j = 0; j < 4; j++) {
                int p = wn + j * 16 + cl;
                float xv = h2f(XT[p * 128 + (((t >> 3) ^ (p & 15)) << 3) + (t & 7)]);
                raw[t * 128 + (((p >> 3) ^ (t & 15)) << 3) + (p & 7)]
                    = f2h(acc[i][j][r] + dco * xv);
            }
        }
    __syncthreads();
    #pragma unroll
    for (int it = 0; it < 4; it++) {
        int id = it * 512 + tid;
        int rr = id >> 4, c8 = id & 15;
        uint4 yv = *(const uint4*)&raw[rr * 128 + ((c8 ^ (rr & 15)) << 3)];
        uint4 zv = *(const uint4*)&zx16[(size_t)(tok0 + rr) * 768 + h * 128 + c8 * 8];
        f16x8 yh = __builtin_bit_cast(f16x8, yv);
        f16x8 zh = __builtin_bit_cast(f16x8, zv);
        union { u16 u[8]; uint4 q; } pk;
        #pragma unroll
        for (int k = 0; k < 8; k++)
            pk.u[k] = f2h((float)yh[k] * silu_f((float)zh[k]));
        *(uint4*)&g16[(size_t)(tok0 + rr) * 256 + h * 128 + c8 * 8] = pk.q;
    }
}

// ---------------------------------------------------------------------------
// out-proj GEMM (K=256, N=128, BM=64) + residual + RMS (+ fused final
// projection in mode 3). (unchanged R13)
// ---------------------------------------------------------------------------
__global__ __launch_bounds__(256) void gemm_outrms_kernel(
    const u16* __restrict__ A, const float* __restrict__ Wf,
    const float* __restrict__ gnw, const float* __restrict__ rmsw,
    u16* __restrict__ xp16, u16* __restrict__ hbuf16, u16* __restrict__ hn16,
    const float* __restrict__ out_wf, const float* __restrict__ out_b,
    float* __restrict__ dout, int mode)
{
    __shared__ u16 sA[64 * 64];
    __shared__ u16 sW[128 * 64];
    __shared__ float red[64][33];
    __shared__ float srstd[64];
    __shared__ float redp[64][5];
    __shared__ float rstdg[64];
    __shared__ u16 hn2[64 * 128];
    __shared__ u16 ow[64 * 128];
    const int K = 256;
    const int m0 = blockIdx.y * 64;
    const int tid = threadIdx.x, wid = tid >> 6, lane = tid & 63;
    const int wm = (wid >> 1) * 32, wn = (wid & 1) * 64;
    const int quad = lane >> 4, cl = lane & 15;
    f32x4 acc[2][4];
    #pragma unroll
    for (int i = 0; i < 2; i++)
        #pragma unroll
        for (int j = 0; j < 4; j++) acc[i][j] = f32x4{0.f, 0.f, 0.f, 0.f};

    float ssq = 0.f;   // per-thread partial sum-of-squares of g (row tid>>2)
    for (int k0 = 0; k0 < K; k0 += 64) {
        #pragma unroll
        for (int i = 0; i < 2; i++) {
            int ck = i * 256 + tid;
            int r = ck >> 3, cc = ck & 7;
            int csw = (cc ^ (r & 7)) << 3;
            async_lds16(A + (size_t)(m0 + r) * K + k0 + csw,
                        (void*)(sA + (i * 256 + (tid & ~63)) * 8));
        }
        #pragma unroll
        for (int i = 0; i < 4; i++) {
            int ck = i * 256 + tid;
            int r = ck >> 3, cc = ck & 7;
            int csw = (cc ^ (r & 7)) << 3;
            *(uint4*)&sW[ck * 8] = cvt8g(Wf + (size_t)r * K + k0 + csw,
                                         gnw + k0 + csw);
        }
        __syncthreads();
        {   // accumulate squares from staged A (swizzle permutes within row)
            int rr = tid >> 2, q = tid & 3;
            f16x8 v0 = *(const f16x8*)&sA[rr * 64 + q * 16];
            f16x8 v1 = *(const f16x8*)&sA[rr * 64 + q * 16 + 8];
            #pragma unroll
            for (int j = 0; j < 8; j++) {
                float a = (float)v0[j], bq = (float)v1[j];
                ssq += a * a + bq * bq;
            }
        }
        #pragma unroll
        for (int ks = 0; ks < 2; ks++) {
            f16x8 af[2], wv[4];
            int kc = ks * 4 + quad;
            #pragma unroll
            for (int i = 0; i < 2; i++) {
                int r = wm + i * 16 + cl;
                af[i] = *(const f16x8*)&sA[r * 64 + ((kc ^ (r & 7)) << 3)];
            }
            #pragma unroll
            for (int j = 0; j < 4; j++) {
                int r = wn + j * 16 + cl;
                wv[j] = *(const f16x8*)&sW[r * 64 + ((kc ^ (r & 7)) << 3)];
            }
            #pragma unroll
            for (int i = 0; i < 2; i++)
                #pragma unroll
                for (int j = 0; j < 4; j++)
                    acc[i][j] = __builtin_amdgcn_mfma_f32_16x16x32_f16(
                        af[i], wv[j], acc[i][j], 0, 0, 0);
        }
        __syncthreads();
    }
    redp[tid >> 2][tid & 3] = ssq;
    __syncthreads();
    if (tid < 64)
        rstdg[tid] = rsqrtf((redp[tid][0] + redp[tid][1] + redp[tid][2]
                             + redp[tid][3]) * (1.f / 256.f) + 1e-5f);
    __syncthreads();
    const int slot = (wid & 1) * 16 + cl;
    #pragma unroll
    for (int i = 0; i < 2; i++)
        #pragma unroll
        for (int r = 0; r < 4; r++) {
            int t = wm + i * 16 + quad * 4 + r;
            size_t ob = (size_t)(m0 + t) * 128;
            float rg = rstdg[t];
            float ssp = 0.f;
            #pragma unroll
            for (int j = 0; j < 4; j++) {
                int n = wn + j * 16 + cl;
                float v = acc[i][j][r] * rg + h2f(hbuf16[ob + n]);
                acc[i][j][r] = v;
                ssp += v * v;
            }
            red[t][slot] = ssp;
        }
    __syncthreads();
    if (tid < 64) {
        float s = 0.f;
        #pragma unroll
        for (int sl = 0; sl < 32; sl++) s += red[tid][sl];
        srstd[tid] = rsqrtf(s * (1.f / 128.f) + 1e-5f);
    }
    __syncthreads();
    #pragma unroll
    for (int i = 0; i < 2; i++)
        #pragma unroll
        for (int r = 0; r < 4; r++) {
            int t = wm + i * 16 + quad * 4 + r;
            size_t ob = (size_t)(m0 + t) * 128;
            float rstd = srstd[t];
            #pragma unroll
            for (int j = 0; j < 4; j++) {
                int n = wn + j * 16 + cl;
                float v = acc[i][j][r];
                float val = v * rstd * rmsw[n];
                if (mode == 1) {
                    hbuf16[ob + n] = f2h(v);
                    hn16[ob + n] = f2h(val);
                } else {
                    val += h2f(xp16[ob + n]);
                    hn2[t * 128 + (((n >> 3) ^ (t & 15)) << 3) + (n & 7)] = f2h(val);
                }
            }
        }
    if (mode == 1) return;
    #pragma unroll
    for (int i = 0; i < 4; i++) {
        int ck = i * 256 + tid;
        int rr = ck >> 4, cc = ck & 15;
        int csw = (cc ^ (rr & 15)) << 3;
        *(uint4*)&ow[ck * 8] = cvt8(out_wf + (size_t)rr * 128 + csw);
    }
    __syncthreads();
    const int wm4 = (wid >> 1) * 32, wn4 = (wid & 1) * 32;
    f32x4 acc2[2][2];
    #pragma unroll
    for (int i = 0; i < 2; i++)
        #pragma unroll
        for (int j = 0; j < 2; j++) acc2[i][j] = f32x4{0.f, 0.f, 0.f, 0.f};
    #pragma unroll
    for (int ks = 0; ks < 4; ks++) {
        f16x8 af2[2], wf2[2];
        int kc = ks * 4 + quad;
        #pragma unroll
        for (int i = 0; i < 2; i++) {
            int r = wm4 + i * 16 + cl;
            af2[i] = *(const f16x8*)&hn2[r * 128 + ((kc ^ (r & 15)) << 3)];
        }
        #pragma unroll
        for (int j = 0; j < 2; j++) {
            int rr = wn4 + j * 16 + cl;
            wf2[j] = *(const f16x8*)&ow[rr * 128 + ((kc ^ (rr & 15)) << 3)];
        }
        #pragma unroll
        for (int i = 0; i < 2; i++)
            #pragma unroll
            for (int j = 0; j < 2; j++)
                acc2[i][j] = __builtin_amdgcn_mfma_f32_16x16x32_f16(
                    af2[i], wf2[j], acc2[i][j], 0, 0, 0);
    }
    #pragma unroll
    for (int i = 0; i < 2; i++) {
        int m = m0 + wm4 + i * 16 + quad * 4;
        #pragma unroll
        for (int j = 0; j < 2; j++) {
            int n = wn4 + j * 16 + cl;
            float bv = out_b[n];
            #pragma unroll
            for (int r = 0; r < 4; r++)
                dout[(size_t)(m + r) * 64 + n] = acc2[i][j][r] + bv;
        }
    }
}

// ---------------------------------------------------------------------------
extern "C" void kernel_launch(void* const* d_in, const int* in_sizes, int n_in,
                              void* d_out, int out_size, void* d_ws, size_t ws_size,
                              hipStream_t stream)
{
    (void)in_sizes; (void)n_in; (void)out_size; (void)ws_size;
    const float* x       = (const float*)d_in[0];
    const float* in_w    = (const float*)d_in[1];
    const float* in_b    = (const float*)d_in[2];
    const float* out_w   = (const float*)d_in[3];
    const float* out_b   = (const float*)d_in[4];
    const float* l_rms_w = (const float*)d_in[5];
    const float* l_in_w  = (const float*)d_in[6];
    const float* conv_w  = (const float*)d_in[7];
    const float* conv_b  = (const float*)d_in[8];
    const float* dt_bias = (const float*)d_in[9];
    const float* A_log   = (const float*)d_in[10];
    const float* D_p     = (const float*)d_in[11];
    const float* gnorm_w = (const float*)d_in[12];
    const float* l_out_w = (const float*)d_in[13];
    const float* fnorm_w = (const float*)d_in[14];

    char* w = (char*)d_ws;
    u16*   xp16   = (u16*)(w);                  // 4.19 MB
    u16*   hbuf16 = (u16*)(w + 4194304);        // 4.19 MB
    u16*   hn16   = (u16*)(w + 8388608);        // 4.19 MB
    u16*   zx16   = (u16*)(w + 12582912);       // 25.17 MB
    float* dtb    = (float*)(w + 37748736);     // 131 KB
    float* Sb     = (float*)(w + 37879808);     // 131 KB
    u16*   Hb     = (u16*)(w + 38010880);       // 8.39 MB
    u16*   Hbf    = (u16*)(w + 46399488);       // 8.39 MB
    u16*   g16    = (u16*)(w + 54788096);       // 8.39 MB

    gemm_rms0_kernel<<<dim3(1, 256), 256, 0, stream>>>(
        x, in_w, in_b, l_rms_w, xp16, hbuf16, hn16);

    for (int i = 0; i < 2; i++) {
        gemm_inproj_kernel<<<dim3(7, 128), 256, 0, stream>>>(
            hn16, l_in_w + (size_t)i * 770 * 128, zx16, dtb, Sb,
            dt_bias + i * 2, A_log + i * 2);
        chunkstate_conv_kernel<<<dim3(32, 2, 4), 512, 0, stream>>>(
            zx16, conv_w + i * 2048, conv_b + i * 512, dtb, Sb, Hb);
        statecombine_kernel<<<dim3(32, 2, 4), 256, 0, stream>>>(Sb, Hb, Hbf);
        ssd_ph_kernel<<<dim3(32, 2, 4), 512, 0, stream>>>(
            zx16, Hbf, dtb, Sb, conv_w + i * 2048, conv_b + i * 512,
            D_p + i * 2, g16);
        gemm_outrms_kernel<<<dim3(1, 256), 256, 0, stream>>>(
            g16, l_out_w + (size_t)i * 128 * 256, gnorm_w + i * 256,
            (i == 0) ? (l_rms_w + 128) : fnorm_w, xp16, hbuf16, hn16,
            out_w, out_b, (float*)d_out, (i == 0) ? 1 : 3);
    }
}

// Round 6
// 225.839 us; speedup vs baseline: 1.7793x; 1.0149x over previous
//
#include <hip/hip_runtime.h>
#include <cstddef>
#include <cstdint>

// MambaDoc — round 19: conv dedup via global handoff (zero new memory).
//  - chunkstate exports unweighted Btok (token-major) and Ctok (h==0 blocks
//    compute the C-conv, previously only done in ssd) to global.
//  - statecombine runs IN-PLACE on Hb (register-prefetch makes it safe);
//    the freed Hbf slot holds Btokg+Ctokg exactly -> ws stays 63.18 MB.
//  - ssd drops its B/C conv rounds; stages Btok+Ctok+Hin in ONE async burst.
//    Barriers 13 -> 8, staging rounds 4 -> 2, two conv passes deleted.
// rms0/inproj/outrms = R18 (passed, 229.2 µs).

#define LSEQ 4096
#define MTOK 16384

typedef unsigned short u16;
typedef _Float16 f16x8 __attribute__((ext_vector_type(8)));
typedef float f32x4 __attribute__((ext_vector_type(4)));

__device__ __forceinline__ u16 f2h(float x) {
    return __builtin_bit_cast(u16, (_Float16)x);
}
__device__ __forceinline__ float h2f(u16 u) {
    return (float)__builtin_bit_cast(_Float16, u);
}
__device__ __forceinline__ float silu_f(float x) { return x / (1.f + __expf(-x)); }

__device__ __forceinline__ void async_lds16(const void* g, void* l) {
    __builtin_amdgcn_global_load_lds(
        (const __attribute__((address_space(1))) unsigned int*)g,
        (__attribute__((address_space(3))) unsigned int*)l, 16, 0, 0);
}

__device__ __forceinline__ uint4 cvt8(const float* __restrict__ src) {
    float4 a = *(const float4*)src;
    float4 b = *(const float4*)(src + 4);
    union { u16 u[8]; uint4 q; } pk;
    pk.u[0] = f2h(a.x); pk.u[1] = f2h(a.y); pk.u[2] = f2h(a.z); pk.u[3] = f2h(a.w);
    pk.u[4] = f2h(b.x); pk.u[5] = f2h(b.y); pk.u[6] = f2h(b.z); pk.u[7] = f2h(b.w);
    return pk.q;
}

__device__ __forceinline__ uint4 cvt8g(const float* __restrict__ src,
                                       const float* __restrict__ gw) {
    float4 a = *(const float4*)src;
    float4 b = *(const float4*)(src + 4);
    float4 ga = *(const float4*)gw;
    float4 gb = *(const float4*)(gw + 4);
    union { u16 u[8]; uint4 q; } pk;
    pk.u[0] = f2h(a.x * ga.x); pk.u[1] = f2h(a.y * ga.y);
    pk.u[2] = f2h(a.z * ga.z); pk.u[3] = f2h(a.w * ga.w);
    pk.u[4] = f2h(b.x * gb.x); pk.u[5] = f2h(b.y * gb.y);
    pk.u[6] = f2h(b.z * gb.z); pk.u[7] = f2h(b.w * gb.w);
    return pk.q;
}

// ---------------------------------------------------------------------------
// Initial projection + fused RMSNorm. BM=64, grid (1,256). (R18)
// ---------------------------------------------------------------------------
__global__ __launch_bounds__(256) void gemm_rms0_kernel(
    const float* __restrict__ xf, const float* __restrict__ wf,
    const float* __restrict__ bias, const float* __restrict__ rmsw,
    u16* __restrict__ xp16, u16* __restrict__ hbuf16, u16* __restrict__ hn16)
{
    __shared__ u16 sA[64 * 64];
    __shared__ u16 sW[128 * 64];
    __shared__ float red[64][33];
    __shared__ float srstd[64];
    const int m0 = blockIdx.y * 64;
    const int tid = threadIdx.x, wid = tid >> 6, lane = tid & 63;
    const int wm = (wid >> 1) * 32, wn = (wid & 1) * 64;
    const int quad = lane >> 4, cl = lane & 15;
    #pragma unroll
    for (int i = 0; i < 2; i++) {
        int ck = i * 256 + tid;
        int r = ck >> 3, cc = ck & 7;
        int csw = (cc ^ (r & 7)) << 3;
        *(uint4*)&sA[ck * 8] = cvt8(xf + (size_t)(m0 + r) * 64 + csw);
    }
    #pragma unroll
    for (int i = 0; i < 4; i++) {
        int ck = i * 256 + tid;
        int r = ck >> 3, cc = ck & 7;
        int csw = (cc ^ (r & 7)) << 3;
        *(uint4*)&sW[ck * 8] = cvt8(wf + (size_t)r * 64 + csw);
    }
    __syncthreads();
    f32x4 acc[2][4];
    #pragma unroll
    for (int i = 0; i < 2; i++)
        #pragma unroll
        for (int j = 0; j < 4; j++) acc[i][j] = f32x4{0.f, 0.f, 0.f, 0.f};
    #pragma unroll
    for (int ks = 0; ks < 2; ks++) {
        f16x8 af[2], wv[4];
        int kc = ks * 4 + quad;
        #pragma unroll
        for (int i = 0; i < 2; i++) {
            int r = wm + i * 16 + cl;
            af[i] = *(const f16x8*)&sA[r * 64 + ((kc ^ (r & 7)) << 3)];
        }
        #pragma unroll
        for (int j = 0; j < 4; j++) {
            int r = wn + j * 16 + cl;
            wv[j] = *(const f16x8*)&sW[r * 64 + ((kc ^ (r & 7)) << 3)];
        }
        #pragma unroll
        for (int i = 0; i < 2; i++)
            #pragma unroll
            for (int j = 0; j < 4; j++)
                acc[i][j] = __builtin_amdgcn_mfma_f32_16x16x32_f16(
                    af[i], wv[j], acc[i][j], 0, 0, 0);
    }
    const int slot = (wid & 1) * 16 + cl;
    #pragma unroll
    for (int i = 0; i < 2; i++)
        #pragma unroll
        for (int r = 0; r < 4; r++) {
            int t = wm + i * 16 + quad * 4 + r;
            float ssp = 0.f;
            #pragma unroll
            for (int j = 0; j < 4; j++) {
                int n = wn + j * 16 + cl;
                float v = acc[i][j][r] + bias[n];
                acc[i][j][r] = v;
                ssp += v * v;
            }
            red[t][slot] = ssp;
        }
    __syncthreads();
    if (tid < 64) {
        float s = 0.f;
        #pragma unroll
        for (int sl = 0; sl < 32; sl++) s += red[tid][sl];
        srstd[tid] = rsqrtf(s * (1.f / 128.f) + 1e-5f);
    }
    __syncthreads();
    #pragma unroll
    for (int i = 0; i < 2; i++)
        #pragma unroll
        for (int r = 0; r < 4; r++) {
            int t = wm + i * 16 + quad * 4 + r;
            #pragma unroll
            for (int j = 0; j < 4; j++) {
                int n = wn + j * 16 + cl;
                sW[t * 128 + (((n >> 3) ^ (t & 15)) << 3) + (n & 7)]
                    = f2h(acc[i][j][r]);
            }
        }
    __syncthreads();
    #pragma unroll
    for (int it = 0; it < 4; it++) {
        int id = it * 256 + tid;
        int rr = id >> 4, c8 = id & 15;
        uint4 v = *(const uint4*)&sW[rr * 128 + ((c8 ^ (rr & 15)) << 3)];
        *(uint4*)&xp16[(size_t)(m0 + rr) * 128 + c8 * 8] = v;
        *(uint4*)&hbuf16[(size_t)(m0 + rr) * 128 + c8 * 8] = v;
    }
    __syncthreads();
    #pragma unroll
    for (int i = 0; i < 2; i++)
        #pragma unroll
        for (int r = 0; r < 4; r++) {
            int t = wm + i * 16 + quad * 4 + r;
            float rstd = srstd[t];
            #pragma unroll
            for (int j = 0; j < 4; j++) {
                int n = wn + j * 16 + cl;
                sW[t * 128 + (((n >> 3) ^ (t & 15)) << 3) + (n & 7)]
                    = f2h(acc[i][j][r] * rstd * rmsw[n]);
            }
        }
    __syncthreads();
    #pragma unroll
    for (int it = 0; it < 4; it++) {
        int id = it * 256 + tid;
        int rr = id >> 4, c8 = id & 15;
        *(uint4*)&hn16[(size_t)(m0 + rr) * 128 + c8 * 8]
            = *(const uint4*)&sW[rr * 128 + ((c8 ^ (rr & 15)) << 3)];
    }
}

// ---------------------------------------------------------------------------
// in_proj GEMM fp16 (K=128). Grid (7, 128). (unchanged)
// ---------------------------------------------------------------------------
__global__ __launch_bounds__(256) void gemm_inproj_kernel(
    const u16* __restrict__ A, const float* __restrict__ Wf,
    u16* __restrict__ zx16, float* __restrict__ dtb, float* __restrict__ Sb,
    const float* __restrict__ dt_bias, const float* __restrict__ A_log)
{
    __shared__ u16 sA[128 * 64];
    __shared__ u16 sW[128 * 64];
    __shared__ float sdt[2][128];
    const int K = 128, N = 770;
    const int n0 = blockIdx.x * 128, m0 = blockIdx.y * 128;
    const int tid = threadIdx.x, wid = tid >> 6, lane = tid & 63;
    const int wm = (wid >> 1) * 64, wn = (wid & 1) * 64;
    const int quad = lane >> 4, cl = lane & 15;
    f32x4 acc[4][4];
    #pragma unroll
    for (int i = 0; i < 4; i++)
        #pragma unroll
        for (int j = 0; j < 4; j++) acc[i][j] = f32x4{0.f, 0.f, 0.f, 0.f};

    for (int k0 = 0; k0 < K; k0 += 64) {
        #pragma unroll
        for (int i = 0; i < 4; i++) {
            int ck = i * 256 + tid;
            int r = ck >> 3, cc = ck & 7;
            int csw = (cc ^ (r & 7)) << 3;
            async_lds16(A + (size_t)(m0 + r) * K + k0 + csw,
                        (void*)(sA + (i * 256 + (tid & ~63)) * 8));
        }
        #pragma unroll
        for (int i = 0; i < 4; i++) {
            int ck = i * 256 + tid;
            int r = ck >> 3, cc = ck & 7;
            int csw = (cc ^ (r & 7)) << 3;
            int rr = n0 + r; if (rr >= N) rr = N - 1;
            *(uint4*)&sW[ck * 8] = cvt8(Wf + (size_t)rr * K + k0 + csw);
        }
        __syncthreads();
        #pragma unroll
        for (int ks = 0; ks < 2; ks++) {
            f16x8 af[4], wv[4];
            int kc = ks * 4 + quad;
            #pragma unroll
            for (int i = 0; i < 4; i++) {
                int r = wm + i * 16 + cl;
                af[i] = *(const f16x8*)&sA[r * 64 + ((kc ^ (r & 7)) << 3)];
            }
            #pragma unroll
            for (int j = 0; j < 4; j++) {
                int r = wn + j * 16 + cl;
                wv[j] = *(const f16x8*)&sW[r * 64 + ((kc ^ (r & 7)) << 3)];
            }
            #pragma unroll
            for (int i = 0; i < 4; i++)
                #pragma unroll
                for (int j = 0; j < 4; j++)
                    acc[i][j] = __builtin_amdgcn_mfma_f32_16x16x32_f16(
                        af[i], wv[j], acc[i][j], 0, 0, 0);
        }
        __syncthreads();
    }
    if (blockIdx.x < 6) {
        #pragma unroll
        for (int i = 0; i < 4; i++) {
            int m = m0 + wm + i * 16 + quad * 4;
            #pragma unroll
            for (int j = 0; j < 4; j++) {
                int n = n0 + wn + j * 16 + cl;
                #pragma unroll
                for (int r = 0; r < 4; r++)
                    zx16[(size_t)(m + r) * 768 + n] = f2h(acc[i][j][r]);
            }
        }
    } else {
        if ((wid & 1) == 0 && cl < 2) {
            #pragma unroll
            for (int i = 0; i < 4; i++)
                #pragma unroll
                for (int r = 0; r < 4; r++)
                    sdt[cl][wm + i * 16 + quad * 4 + r] = acc[i][0][r];
        }
        __syncthreads();
        const int hh = tid >> 7, t = tid & 127;
        float raw = sdt[hh][t] + dt_bias[hh];
        float dt = fmaxf(raw, 0.f) + log1pf(__expf(-fabsf(raw)));
        dtb[(size_t)(m0 + t) * 2 + hh] = dt;
        float ad = -__expf(A_log[hh]) * dt;
        __syncthreads();
        sdt[hh][t] = ad;
        __syncthreads();
        for (int off = 1; off < 128; off <<= 1) {
            float add = (t >= off) ? sdt[hh][t - off] : 0.f;
            __syncthreads();
            sdt[hh][t] += add;
            __syncthreads();
        }
        Sb[(size_t)(m0 + t) * 2 + hh] = sdt[hh][t];
    }
}

// ---------------------------------------------------------------------------
// chunkstate + conv. Grid (32,2,4), 512 thr.
// R19: exports unweighted Btok (token-major) and, for h==0 blocks, runs the
// C-conv round exporting Ctok (token-major) — ssd consumes these directly.
// ---------------------------------------------------------------------------
__global__ __launch_bounds__(512) void chunkstate_conv_kernel(
    const u16* __restrict__ zx16, const float* __restrict__ cw,
    const float* __restrict__ cb, const float* __restrict__ dtb,
    const float* __restrict__ Sb, u16* __restrict__ Hb,
    u16* __restrict__ Btokg, u16* __restrict__ Ctokg)
{
    __shared__ u16 raw[2560 * 8];
    __shared__ u16 XT[128 * 128];
    __shared__ u16 BT[128 * 128];
    __shared__ float scw[3][128][4];
    __shared__ float scb[3][128];
    __shared__ float ssw[128];
    const int c = blockIdx.x, h = blockIdx.y, b = blockIdx.z;
    const int tid = threadIdx.x, wid = tid >> 6, lane = tid & 63;
    const int quad = lane >> 4, cl = lane & 15;
    const int tok0 = b * LSEQ + c * 128;
    const size_t blkBC = ((size_t)(b * 32 + c)) << 14;
    for (int idx = tid; idx < 384; idx += 512) {
        int grp = idx >> 7, j = idx & 127;
        int ch = (grp == 0) ? (128 * h + j) : (grp == 1 ? 256 + j : 384 + j);
        float4 w4 = *(const float4*)&cw[ch * 4];
        scw[grp][j][0] = w4.x; scw[grp][j][1] = w4.y;
        scw[grp][j][2] = w4.z; scw[grp][j][3] = w4.w;
        scb[grp][j] = cb[ch];
    }
    if (tid < 128) {
        float Sl = Sb[(size_t)(tok0 + 127) * 2 + h];
        ssw[tid] = __expf(Sl - Sb[(size_t)(tok0 + tid) * 2 + h])
                   * dtb[(size_t)(tok0 + tid) * 2 + h];
    }
    // ---- conv X -> XT
    #pragma unroll
    for (int i = 0; i < 5; i++) {
        int ck = i * 512 + tid;
        int r = ck >> 4; if (r > 130) r = 130;
        int cc = ck & 15;
        int tok = tok0 - 3 + r; if (tok < 0) tok = 0;
        async_lds16(zx16 + (size_t)tok * 768 + 256 + 128 * h + ((cc ^ (r & 15)) << 3),
                    (void*)(raw + (i * 512 + (tid & ~63)) * 8));
    }
    __syncthreads();
    if (c == 0 && tid < 48) *(uint4*)&raw[tid * 8] = make_uint4(0, 0, 0, 0);
    __syncthreads();
    #pragma unroll
    for (int it = 0; it < 4; it++) {
        int idx = it * 512 + tid;
        int s = idx & 127, pg = idx >> 7;
        f16x8 v[4];
        #pragma unroll
        for (int k = 0; k < 4; k++) {
            int rr = s + k;
            v[k] = *(const f16x8*)&raw[rr * 128 + ((pg ^ (rr & 15)) << 3)];
        }
        #pragma unroll
        for (int j = 0; j < 8; j++) {
            int p = pg * 8 + j;
            float o = scb[0][p] + (float)v[0][j] * scw[0][p][0]
                    + (float)v[1][j] * scw[0][p][1]
                    + (float)v[2][j] * scw[0][p][2]
                    + (float)v[3][j] * scw[0][p][3];
            o = silu_f(o);
            XT[p * 128 + (((s >> 3) ^ (p & 15)) << 3) + (s & 7)] = f2h(o);
        }
    }
    __syncthreads();
    // ---- conv B -> BT (weighted, n-major) + export unweighted Btok (h==0)
    #pragma unroll
    for (int i = 0; i < 5; i++) {
        int ck = i * 512 + tid;
        int r = ck >> 4; if (r > 130) r = 130;
        int cc = ck & 15;
        int tok = tok0 - 3 + r; if (tok < 0) tok = 0;
        async_lds16(zx16 + (size_t)tok * 768 + 512 + ((cc ^ (r & 15)) << 3),
                    (void*)(raw + (i * 512 + (tid & ~63)) * 8));
    }
    __syncthreads();
    if (c == 0 && tid < 48) *(uint4*)&raw[tid * 8] = make_uint4(0, 0, 0, 0);
    __syncthreads();
    #pragma unroll
    for (int it = 0; it < 4; it++) {
        int idx = it * 512 + tid;
        int s = idx & 127, ng = idx >> 7;
        f16x8 v[4];
        #pragma unroll
        for (int k = 0; k < 4; k++) {
            int rr = s + k;
            v[k] = *(const f16x8*)&raw[rr * 128 + ((ng ^ (rr & 15)) << 3)];
        }
        float wsv = ssw[s];
        union { u16 u[8]; uint4 q; } pk;
        #pragma unroll
        for (int j = 0; j < 8; j++) {
            int n = ng * 8 + j;
            float o = scb[1][n] + (float)v[0][j] * scw[1][n][0]
                    + (float)v[1][j] * scw[1][n][1]
                    + (float)v[2][j] * scw[1][n][2]
                    + (float)v[3][j] * scw[1][n][3];
            float osl = silu_f(o);
            pk.u[j] = f2h(osl);
            BT[n * 128 + (((s >> 3) ^ (n & 15)) << 3) + (s & 7)] = f2h(osl * wsv);
        }
        if (h == 0)
            *(uint4*)&Btokg[blkBC + (size_t)s * 128 + ng * 8] = pk.q;
    }
    // ---- C-conv export round (h==0 blocks only; whole block uniform)
    if (h == 0) {
        __syncthreads();   // B-conv reads of raw done before re-stage
        #pragma unroll
        for (int i = 0; i < 5; i++) {
            int ck = i * 512 + tid;
            int r = ck >> 4; if (r > 130) r = 130;
            int cc = ck & 15;
            int tok = tok0 - 3 + r; if (tok < 0) tok = 0;
            async_lds16(zx16 + (size_t)tok * 768 + 640 + ((cc ^ (r & 15)) << 3),
                        (void*)(raw + (i * 512 + (tid & ~63)) * 8));
        }
        __syncthreads();
        if (c == 0 && tid < 48) *(uint4*)&raw[tid * 8] = make_uint4(0, 0, 0, 0);
        __syncthreads();
        #pragma unroll
        for (int it = 0; it < 4; it++) {
            int idx = it * 512 + tid;
            int t = idx & 127, ng = idx >> 7;
            f16x8 v[4];
            #pragma unroll
            for (int k = 0; k < 4; k++) {
                int rr = t + k;
                v[k] = *(const f16x8*)&raw[rr * 128 + ((ng ^ (rr & 15)) << 3)];
            }
            union { u16 u[8]; uint4 q; } pk;
            #pragma unroll
            for (int j = 0; j < 8; j++) {
                int n = ng * 8 + j;
                float o = scb[2][n] + (float)v[0][j] * scw[2][n][0]
                        + (float)v[1][j] * scw[2][n][1]
                        + (float)v[2][j] * scw[2][n][2]
                        + (float)v[3][j] * scw[2][n][3];
                pk.u[j] = f2h(silu_f(o));
            }
            *(uint4*)&Ctokg[blkBC + (size_t)t * 128 + ng * 8] = pk.q;
        }
    }
    __syncthreads();   // XT/BT visible for GEMM (both h paths)
    // ---- GEMM: Hb[p][n] = sum_s XT[p,s] * BT[n,s]
    const size_t blk = ((size_t)((b * 2 + h) * 32 + c)) << 14;
    const int wm = (wid >> 1) * 32, wn = (wid & 1) * 64;
    f32x4 acc[2][4];
    #pragma unroll
    for (int i = 0; i < 2; i++)
        #pragma unroll
        for (int j = 0; j < 4; j++) acc[i][j] = f32x4{0.f, 0.f, 0.f, 0.f};
    #pragma unroll
    for (int ks = 0; ks < 4; ks++) {
        f16x8 xa[2], bb[4];
        int kc = ks * 4 + quad;
        #pragma unroll
        for (int i = 0; i < 2; i++) {
            int r = wm + i * 16 + cl;
            xa[i] = *(const f16x8*)&XT[r * 128 + ((kc ^ (r & 15)) << 3)];
        }
        #pragma unroll
        for (int j = 0; j < 4; j++) {
            int r = wn + j * 16 + cl;
            bb[j] = *(const f16x8*)&BT[r * 128 + ((kc ^ (r & 15)) << 3)];
        }
        #pragma unroll
        for (int i = 0; i < 2; i++)
            #pragma unroll
            for (int j = 0; j < 4; j++)
                acc[i][j] = __builtin_amdgcn_mfma_f32_16x16x32_f16(
                    xa[i], bb[j], acc[i][j], 0, 0, 0);
    }
    __syncthreads();   // all GEMM reads done before raw reuse (h==1 path too)
    // transpose acc through raw, then coalesced stores
    #pragma unroll
    for (int i = 0; i < 2; i++)
        #pragma unroll
        for (int j = 0; j < 4; j++)
            #pragma unroll
            for (int r = 0; r < 4; r++) {
                int p = wm + i * 16 + quad * 4 + r;
                int n = wn + j * 16 + cl;
                raw[p * 128 + (((n >> 3) ^ (p & 15)) << 3) + (n & 7)]
                    = f2h(acc[i][j][r]);
            }
    __syncthreads();
    u16* out = Hb + blk;
    #pragma unroll
    for (int it = 0; it < 4; it++) {
        int id = it * 512 + tid;
        int rr = id >> 4, c8 = id & 15;
        *(uint4*)&out[(size_t)rr * 128 + c8 * 8]
            = *(const uint4*)&raw[rr * 128 + ((c8 ^ (rr & 15)) << 3)];
    }
}

// ---------------------------------------------------------------------------
// Inter-chunk combine — register-prefetch, IN-PLACE on Hb. Grid (32,2,4).
// All 32 chunk values are loaded to registers before any store; each thread
// owns its element exclusively -> src==dst safe (single pointer, no restrict).
// ---------------------------------------------------------------------------
__global__ __launch_bounds__(256) void statecombine_kernel(
    const float* __restrict__ Sb, u16* Hbuf)
{
    __shared__ float sdec[32];
    const int h = blockIdx.y, b = blockIdx.z;
    const int e2 = blockIdx.x * 256 + threadIdx.x;
    if (threadIdx.x < 32)
        sdec[threadIdx.x] =
            __expf(Sb[(size_t)(b * LSEQ + threadIdx.x * 128 + 127) * 2 + h]);
    const size_t base2 = ((size_t)((b * 2 + h) * 32)) << 13;
    unsigned int* buf = (unsigned int*)Hbuf;
    unsigned int v[32];
    #pragma unroll
    for (int c = 0; c < 32; c++)
        v[c] = buf[base2 + ((size_t)c << 13) + e2];
    __syncthreads();
    float s0 = 0.f, s1 = 0.f;
    #pragma unroll
    for (int c = 0; c < 32; c++) {
        union { u16 u[2]; unsigned int q; } pk;
        pk.u[0] = f2h(s0); pk.u[1] = f2h(s1);
        buf[base2 + ((size_t)c << 13) + e2] = pk.q;
        float d = sdec[c];
        s0 = d * s0 + h2f((u16)(v[c] & 0xffffu));
        s1 = d * s1 + h2f((u16)(v[c] >> 16));
    }
}

// ---------------------------------------------------------------------------
// Per-head fused SSD. Grid (32,2,4), 512 thr, ~139 KB LDS.
// R19: only the X-conv remains; Btok/Ctok come precomputed from chunkstate,
// staged together with Hin in ONE async burst. G overwrites Btok after C2.
// ---------------------------------------------------------------------------
__global__ __launch_bounds__(512) void ssd_ph_kernel(
    const u16* __restrict__ zx16, const u16* __restrict__ Hin,
    const float* __restrict__ dtb, const float* __restrict__ Sb,
    const float* __restrict__ cw, const float* __restrict__ cb,
    const float* __restrict__ Dp, u16* __restrict__ g16,
    const u16* __restrict__ Btokg, const u16* __restrict__ Ctokg)
{
    __shared__ u16 raw[2560 * 8];     // X staging -> Hin -> Y
    __shared__ u16 XT[128 * 128];
    __shared__ u16 Btok[128 * 128];   // B (token-major) -> G after C2
    __shared__ u16 Ctok[128 * 128];
    __shared__ float sS[128], sdt[128];
    __shared__ float scwX[128][4];
    __shared__ float scbX[128];
    const int c = blockIdx.x, h = blockIdx.y, b = blockIdx.z;
    const int tid = threadIdx.x, wid = tid >> 6, lane = tid & 63;
    const int quad = lane >> 4, cl = lane & 15;
    const int tok0 = b * LSEQ + c * 128;
    const size_t blkH = ((size_t)((b * 2 + h) * 32 + c)) << 14;
    const size_t blkBC = ((size_t)(b * 32 + c)) << 14;
    if (tid < 128) {
        int ch = 128 * h + tid;
        float4 w4 = *(const float4*)&cw[ch * 4];
        scwX[tid][0] = w4.x; scwX[tid][1] = w4.y;
        scwX[tid][2] = w4.z; scwX[tid][3] = w4.w;
        scbX[tid] = cb[ch];
        sS[tid] = Sb[(size_t)(tok0 + tid) * 2 + h];
        sdt[tid] = dtb[(size_t)(tok0 + tid) * 2 + h];
    }
    // ---- stage X rows
    #pragma unroll
    for (int i = 0; i < 5; i++) {
        int ck = i * 512 + tid;
        int r = ck >> 4; if (r > 130) r = 130;
        int cc = ck & 15;
        int tok = tok0 - 3 + r; if (tok < 0) tok = 0;
        async_lds16(zx16 + (size_t)tok * 768 + 256 + 128 * h + ((cc ^ (r & 15)) << 3),
                    (void*)(raw + (i * 512 + (tid & ~63)) * 8));
    }
    __syncthreads();
    if (c == 0 && tid < 48) *(uint4*)&raw[tid * 8] = make_uint4(0, 0, 0, 0);
    __syncthreads();
    // ---- conv X -> XT
    #pragma unroll
    for (int it = 0; it < 4; it++) {
        int idx = it * 512 + tid;
        int s = idx & 127, pg = idx >> 7;
        f16x8 v[4];
        #pragma unroll
        for (int k = 0; k < 4; k++) {
            int rr = s + k;
            v[k] = *(const f16x8*)&raw[rr * 128 + ((pg ^ (rr & 15)) << 3)];
        }
        #pragma unroll
        for (int j = 0; j < 8; j++) {
            int p = pg * 8 + j;
            float o = scbX[p] + (float)v[0][j] * scwX[p][0]
                    + (float)v[1][j] * scwX[p][1]
                    + (float)v[2][j] * scwX[p][2]
                    + (float)v[3][j] * scwX[p][3];
            XT[p * 128 + (((s >> 3) ^ (p & 15)) << 3) + (s & 7)] = f2h(silu_f(o));
        }
    }
    __syncthreads();   // raw(X) reads done -> safe to overwrite with Hin
    // ---- ONE combined staging burst: Btok, Ctok, Hin
    #pragma unroll
    for (int i = 0; i < 4; i++) {
        int ck = i * 512 + tid;
        int r = ck >> 4, cc = ck & 15;
        size_t so = (size_t)r * 128 + ((cc ^ (r & 15)) << 3);
        int ldso = (i * 512 + (tid & ~63)) * 8;
        async_lds16(Btokg + blkBC + so, (void*)(Btok + ldso));
        async_lds16(Ctokg + blkBC + so, (void*)(Ctok + ldso));
        async_lds16(Hin + blkH + so, (void*)(raw + ldso));
    }
    __syncthreads();
    // ---- phase 1: Y = C @ Hin^T ; scale by exp(S_t)
    const int wm = (wid >> 1) * 32, wn = (wid & 1) * 64;
    f32x4 acc[2][4];
    #pragma unroll
    for (int i = 0; i < 2; i++)
        #pragma unroll
        for (int j = 0; j < 4; j++) acc[i][j] = f32x4{0.f, 0.f, 0.f, 0.f};
    #pragma unroll
    for (int ks = 0; ks < 4; ks++) {
        f16x8 ca[2], hb[4];
        int kc = ks * 4 + quad;
        #pragma unroll
        for (int i = 0; i < 2; i++) {
            int r = wm + i * 16 + cl;
            ca[i] = *(const f16x8*)&Ctok[r * 128 + ((kc ^ (r & 15)) << 3)];
        }
        #pragma unroll
        for (int j = 0; j < 4; j++) {
            int r = wn + j * 16 + cl;
            hb[j] = *(const f16x8*)&raw[r * 128 + ((kc ^ (r & 15)) << 3)];
        }
        #pragma unroll
        for (int i = 0; i < 2; i++)
            #pragma unroll
            for (int j = 0; j < 4; j++)
                acc[i][j] = __builtin_amdgcn_mfma_f32_16x16x32_f16(
                    ca[i], hb[j], acc[i][j], 0, 0, 0);
    }
    #pragma unroll
    for (int i = 0; i < 2; i++)
        #pragma unroll
        for (int r = 0; r < 4; r++) {
            float e = __expf(sS[wm + i * 16 + quad * 4 + r]);
            #pragma unroll
            for (int j = 0; j < 4; j++) acc[i][j][r] *= e;
        }
    // ---- phase 2: S = C @ B^T (triangular skip)
    f32x4 sacc[2][4];
    #pragma unroll
    for (int i = 0; i < 2; i++)
        #pragma unroll
        for (int j = 0; j < 4; j++) sacc[i][j] = f32x4{0.f, 0.f, 0.f, 0.f};
    #pragma unroll
    for (int ks = 0; ks < 4; ks++) {
        f16x8 cs[2], bs[4];
        int kc = ks * 4 + quad;
        #pragma unroll
        for (int i2 = 0; i2 < 2; i2++) {
            int r = wm + i2 * 16 + cl;
            cs[i2] = *(const f16x8*)&Ctok[r * 128 + ((kc ^ (r & 15)) << 3)];
        }
        #pragma unroll
        for (int j = 0; j < 4; j++) {
            int r = wn + j * 16 + cl;
            bs[j] = *(const f16x8*)&Btok[r * 128 + ((kc ^ (r & 15)) << 3)];
        }
        #pragma unroll
        for (int i2 = 0; i2 < 2; i2++)
            #pragma unroll
            for (int j = 0; j < 4; j++)
                if (wm + i2 * 16 + 15 >= wn + j * 16)
                    sacc[i2][j] = __builtin_amdgcn_mfma_f32_16x16x32_f16(
                        cs[i2], bs[j], sacc[i2][j], 0, 0, 0);
    }
    __syncthreads();   // all reads of Btok (C2) and raw/Hin (C1) done
    // ---- G = mask ∘ S ∘ exp(St-Ss) ∘ dt_s  -> Btok (dead after C2)
    #pragma unroll
    for (int i2 = 0; i2 < 2; i2++)
        #pragma unroll
        for (int r = 0; r < 4; r++) {
            int t = wm + i2 * 16 + quad * 4 + r;
            float Stv = sS[t];
            #pragma unroll
            for (int j = 0; j < 4; j++) {
                int s = wn + j * 16 + cl;
                float gv = 0.f;
                if (s <= t) gv = sacc[i2][j][r] * __expf(Stv - sS[s]) * sdt[s];
                Btok[t * 128 + (((s >> 3) ^ (t & 15)) << 3) + (s & 7)] = f2h(gv);
            }
        }
    __syncthreads();
    // ---- phase 3: Y += G @ X
    #pragma unroll
    for (int ks = 0; ks < 4; ks++) {
        f16x8 ga[2], xb[4];
        int kc = ks * 4 + quad;
        #pragma unroll
        for (int i = 0; i < 2; i++) {
            int r = wm + i * 16 + cl;
            ga[i] = *(const f16x8*)&Btok[r * 128 + ((kc ^ (r & 15)) << 3)];
        }
        #pragma unroll
        for (int j = 0; j < 4; j++) {
            int r = wn + j * 16 + cl;
            xb[j] = *(const f16x8*)&XT[r * 128 + ((kc ^ (r & 15)) << 3)];
        }
        #pragma unroll
        for (int i = 0; i < 2; i++)
            #pragma unroll
            for (int j = 0; j < 4; j++)
                acc[i][j] = __builtin_amdgcn_mfma_f32_16x16x32_f16(
                    ga[i], xb[j], acc[i][j], 0, 0, 0);
    }
    // ---- epilogue: Y + D*x -> raw [t][p] (Hin dead since the C2 barrier)
    const float dco = Dp[h];
    #pragma unroll
    for (int i = 0; i < 2; i++)
        #pragma unroll
        for (int r = 0; r < 4; r++) {
            int t = wm + i * 16 + quad * 4 + r;
            #pragma unroll
            for (int j = 0; j < 4; j++) {
                int p = wn + j * 16 + cl;
                float xv = h2f(XT[p * 128 + (((t >> 3) ^ (p & 15)) << 3) + (t & 7)]);
                raw[t * 128 + (((p >> 3) ^ (t & 15)) << 3) + (p & 7)]
                    = f2h(acc[i][j][r] + dco * xv);
            }
        }
    __syncthreads();
    #pragma unroll
    for (int it = 0; it < 4; it++) {
        int id = it * 512 + tid;
        int rr = id >> 4, c8 = id & 15;
        uint4 yv = *(const uint4*)&raw[rr * 128 + ((c8 ^ (rr & 15)) << 3)];
        uint4 zv = *(const uint4*)&zx16[(size_t)(tok0 + rr) * 768 + h * 128 + c8 * 8];
        f16x8 yh = __builtin_bit_cast(f16x8, yv);
        f16x8 zh = __builtin_bit_cast(f16x8, zv);
        union { u16 u[8]; uint4 q; } pk;
        #pragma unroll
        for (int k = 0; k < 8; k++)
            pk.u[k] = f2h((float)yh[k] * silu_f((float)zh[k]));
        *(uint4*)&g16[(size_t)(tok0 + rr) * 256 + h * 128 + c8 * 8] = pk.q;
    }
}

// ---------------------------------------------------------------------------
// out-proj GEMM (K=256, N=128, BM=64) + residual + RMS (+ fused final
// projection in mode 3). (unchanged)
// ---------------------------------------------------------------------------
__global__ __launch_bounds__(256) void gemm_outrms_kernel(
    const u16* __restrict__ A, const float* __restrict__ Wf,
    const float* __restrict__ gnw, const float* __restrict__ rmsw,
    u16* __restrict__ xp16, u16* __restrict__ hbuf16, u16* __restrict__ hn16,
    const float* __restrict__ out_wf, const float* __restrict__ out_b,
    float* __restrict__ dout, int mode)
{
    __shared__ u16 sA[64 * 64];
    __shared__ u16 sW[128 * 64];
    __shared__ float red[64][33];
    __shared__ float srstd[64];
    __shared__ float redp[64][5];
    __shared__ float rstdg[64];
    __shared__ u16 hn2[64 * 128];
    __shared__ u16 ow[64 * 128];
    const int K = 256;
    const int m0 = blockIdx.y * 64;
    const int tid = threadIdx.x, wid = tid >> 6, lane = tid & 63;
    const int wm = (wid >> 1) * 32, wn = (wid & 1) * 64;
    const int quad = lane >> 4, cl = lane & 15;
    f32x4 acc[2][4];
    #pragma unroll
    for (int i = 0; i < 2; i++)
        #pragma unroll
        for (int j = 0; j < 4; j++) acc[i][j] = f32x4{0.f, 0.f, 0.f, 0.f};

    float ssq = 0.f;
    for (int k0 = 0; k0 < K; k0 += 64) {
        #pragma unroll
        for (int i = 0; i < 2; i++) {
            int ck = i * 256 + tid;
            int r = ck >> 3, cc = ck & 7;
            int csw = (cc ^ (r & 7)) << 3;
            async_lds16(A + (size_t)(m0 + r) * K + k0 + csw,
                        (void*)(sA + (i * 256 + (tid & ~63)) * 8));
        }
        #pragma unroll
        for (int i = 0; i < 4; i++) {
            int ck = i * 256 + tid;
            int r = ck >> 3, cc = ck & 7;
            int csw = (cc ^ (r & 7)) << 3;
            *(uint4*)&sW[ck * 8] = cvt8g(Wf + (size_t)r * K + k0 + csw,
                                         gnw + k0 + csw);
        }
        __syncthreads();
        {
            int rr = tid >> 2, q = tid & 3;
            f16x8 v0 = *(const f16x8*)&sA[rr * 64 + q * 16];
            f16x8 v1 = *(const f16x8*)&sA[rr * 64 + q * 16 + 8];
            #pragma unroll
            for (int j = 0; j < 8; j++) {
                float a = (float)v0[j], bq = (float)v1[j];
                ssq += a * a + bq * bq;
            }
        }
        #pragma unroll
        for (int ks = 0; ks < 2; ks++) {
            f16x8 af[2], wv[4];
            int kc = ks * 4 + quad;
            #pragma unroll
            for (int i = 0; i < 2; i++) {
                int r = wm + i * 16 + cl;
                af[i] = *(const f16x8*)&sA[r * 64 + ((kc ^ (r & 7)) << 3)];
            }
            #pragma unroll
            for (int j = 0; j < 4; j++) {
                int r = wn + j * 16 + cl;
                wv[j] = *(const f16x8*)&sW[r * 64 + ((kc ^ (r & 7)) << 3)];
            }
            #pragma unroll
            for (int i = 0; i < 2; i++)
                #pragma unroll
                for (int j = 0; j < 4; j++)
                    acc[i][j] = __builtin_amdgcn_mfma_f32_16x16x32_f16(
                        af[i], wv[j], acc[i][j], 0, 0, 0);
        }
        __syncthreads();
    }
    redp[tid >> 2][tid & 3] = ssq;
    __syncthreads();
    if (tid < 64)
        rstdg[tid] = rsqrtf((redp[tid][0] + redp[tid][1] + redp[tid][2]
                             + redp[tid][3]) * (1.f / 256.f) + 1e-5f);
    __syncthreads();
    const int slot = (wid & 1) * 16 + cl;
    #pragma unroll
    for (int i = 0; i < 2; i++)
        #pragma unroll
        for (int r = 0; r < 4; r++) {
            int t = wm + i * 16 + quad * 4 + r;
            size_t ob = (size_t)(m0 + t) * 128;
            float rg = rstdg[t];
            float ssp = 0.f;
            #pragma unroll
            for (int j = 0; j < 4; j++) {
                int n = wn + j * 16 + cl;
                float v = acc[i][j][r] * rg + h2f(hbuf16[ob + n]);
                acc[i][j][r] = v;
                ssp += v * v;
            }
            red[t][slot] = ssp;
        }
    __syncthreads();
    if (tid < 64) {
        float s = 0.f;
        #pragma unroll
        for (int sl = 0; sl < 32; sl++) s += red[tid][sl];
        srstd[tid] = rsqrtf(s * (1.f / 128.f) + 1e-5f);
    }
    __syncthreads();
    #pragma unroll
    for (int i = 0; i < 2; i++)
        #pragma unroll
        for (int r = 0; r < 4; r++) {
            int t = wm + i * 16 + quad * 4 + r;
            size_t ob = (size_t)(m0 + t) * 128;
            float rstd = srstd[t];
            #pragma unroll
            for (int j = 0; j < 4; j++) {
                int n = wn + j * 16 + cl;
                float v = acc[i][j][r];
                float val = v * rstd * rmsw[n];
                if (mode == 1) {
                    hbuf16[ob + n] = f2h(v);
                    hn16[ob + n] = f2h(val);
                } else {
                    val += h2f(xp16[ob + n]);
                    hn2[t * 128 + (((n >> 3) ^ (t & 15)) << 3) + (n & 7)] = f2h(val);
                }
            }
        }
    if (mode == 1) return;
    #pragma unroll
    for (int i = 0; i < 4; i++) {
        int ck = i * 256 + tid;
        int rr = ck >> 4, cc = ck & 15;
        int csw = (cc ^ (rr & 15)) << 3;
        *(uint4*)&ow[ck * 8] = cvt8(out_wf + (size_t)rr * 128 + csw);
    }
    __syncthreads();
    const int wm4 = (wid >> 1) * 32, wn4 = (wid & 1) * 32;
    f32x4 acc2[2][2];
    #pragma unroll
    for (int i = 0; i < 2; i++)
        #pragma unroll
        for (int j = 0; j < 2; j++) acc2[i][j] = f32x4{0.f, 0.f, 0.f, 0.f};
    #pragma unroll
    for (int ks = 0; ks < 4; ks++) {
        f16x8 af2[2], wf2[2];
        int kc = ks * 4 + quad;
        #pragma unroll
        for (int i = 0; i < 2; i++) {
            int r = wm4 + i * 16 + cl;
            af2[i] = *(const f16x8*)&hn2[r * 128 + ((kc ^ (r & 15)) << 3)];
        }
        #pragma unroll
        for (int j = 0; j < 2; j++) {
            int rr = wn4 + j * 16 + cl;
            wf2[j] = *(const f16x8*)&ow[rr * 128 + ((kc ^ (rr & 15)) << 3)];
        }
        #pragma unroll
        for (int i = 0; i < 2; i++)
            #pragma unroll
            for (int j = 0; j < 2; j++)
                acc2[i][j] = __builtin_amdgcn_mfma_f32_16x16x32_f16(
                    af2[i], wf2[j], acc2[i][j], 0, 0, 0);
    }
    #pragma unroll
    for (int i = 0; i < 2; i++) {
        int m = m0 + wm4 + i * 16 + quad * 4;
        #pragma unroll
        for (int j = 0; j < 2; j++) {
            int n = wn4 + j * 16 + cl;
            float bv = out_b[n];
            #pragma unroll
            for (int r = 0; r < 4; r++)
                dout[(size_t)(m + r) * 64 + n] = acc2[i][j][r] + bv;
        }
    }
}

// ---------------------------------------------------------------------------
extern "C" void kernel_launch(void* const* d_in, const int* in_sizes, int n_in,
                              void* d_out, int out_size, void* d_ws, size_t ws_size,
                              hipStream_t stream)
{
    (void)in_sizes; (void)n_in; (void)out_size; (void)ws_size;
    const float* x       = (const float*)d_in[0];
    const float* in_w    = (const float*)d_in[1];
    const float* in_b    = (const float*)d_in[2];
    const float* out_w   = (const float*)d_in[3];
    const float* out_b   = (const float*)d_in[4];
    const float* l_rms_w = (const float*)d_in[5];
    const float* l_in_w  = (const float*)d_in[6];
    const float* conv_w  = (const float*)d_in[7];
    const float* conv_b  = (const float*)d_in[8];
    const float* dt_bias = (const float*)d_in[9];
    const float* A_log   = (const float*)d_in[10];
    const float* D_p     = (const float*)d_in[11];
    const float* gnorm_w = (const float*)d_in[12];
    const float* l_out_w = (const float*)d_in[13];
    const float* fnorm_w = (const float*)d_in[14];

    char* w = (char*)d_ws;
    u16*   xp16   = (u16*)(w);                  // 4.19 MB
    u16*   hbuf16 = (u16*)(w + 4194304);        // 4.19 MB
    u16*   hn16   = (u16*)(w + 8388608);        // 4.19 MB
    u16*   zx16   = (u16*)(w + 12582912);       // 25.17 MB
    float* dtb    = (float*)(w + 37748736);     // 131 KB
    float* Sb     = (float*)(w + 37879808);     // 131 KB
    u16*   Hb     = (u16*)(w + 38010880);       // 8.39 MB (in-place combined)
    u16*   Btokg  = (u16*)(w + 46399488);       // 4.19 MB (was Hbf lo-half)
    u16*   Ctokg  = (u16*)(w + 50593792);       // 4.19 MB (was Hbf hi-half)
    u16*   g16    = (u16*)(w + 54788096);       // 8.39 MB

    gemm_rms0_kernel<<<dim3(1, 256), 256, 0, stream>>>(
        x, in_w, in_b, l_rms_w, xp16, hbuf16, hn16);

    for (int i = 0; i < 2; i++) {
        gemm_inproj_kernel<<<dim3(7, 128), 256, 0, stream>>>(
            hn16, l_in_w + (size_t)i * 770 * 128, zx16, dtb, Sb,
            dt_bias + i * 2, A_log + i * 2);
        chunkstate_conv_kernel<<<dim3(32, 2, 4), 512, 0, stream>>>(
            zx16, conv_w + i * 2048, conv_b + i * 512, dtb, Sb, Hb,
            Btokg, Ctokg);
        statecombine_kernel<<<dim3(32, 2, 4), 256, 0, stream>>>(Sb, Hb);
        ssd_ph_kernel<<<dim3(32, 2, 4), 512, 0, stream>>>(
            zx16, Hb, dtb, Sb, conv_w + i * 2048, conv_b + i * 512,
            D_p + i * 2, g16, Btokg, Ctokg);
        gemm_outrms_kernel<<<dim3(1, 256), 256, 0, stream>>>(
            g16, l_out_w + (size_t)i * 128 * 256, gnorm_w + i * 256,
            (i == 0) ? (l_rms_w + 128) : fnorm_w, xp16, hbuf16, hn16,
            out_w, out_b, (float*)d_out, (i == 0) ? 1 : 3);
    }
}